// Round 14
// baseline (176.142 us; speedup 1.0000x reference)
//
#include <hip/hip_runtime.h>
#include <cstdint>
#include <cstddef>

#define NN 8000
#define EE 64000
#define HH 10

// wbuf (unsigned short) offsets
#define OFF_W5T 0      // PERMUTED: W5T[c'][k] = W5[cb(k)][c']
#define OFF_WNQ 4096
#define OFF_WNQL 8192
#define OFF_WNK 12288
#define OFF_WNKL 16384
#define OFF_WNV 20480
#define OFF_WNVL 24576
#define OFF_W4B 28672  // PERMUTED: W4B[c'][k] = W4[64+cb(k)][c']
#define OFF_W4T 32768
#define OFF_WSRC 36864
#define OFF_WSRCL 77824

typedef __attribute__((ext_vector_type(8))) short bf16x8;
typedef __attribute__((ext_vector_type(4))) float f32x4;
typedef __attribute__((ext_vector_type(4))) unsigned int u32x4;

__device__ __forceinline__ int rfl(int v) { return __builtin_amdgcn_readfirstlane(v); }

// Contraction-index permutation: position k (= 32ks+8g+i) holds true channel
// cb(k) = 32ks + 16*(i>=4) + 4g + (i&3). Bijective within each 32-slice ->
// C-layout regs pack DIRECTLY into B-frags when weights use cb too (r13-verified).
__device__ __forceinline__ int cbperm(int k) {
  return 32 * (k >> 5) + 16 * ((k >> 2) & 1) + 4 * ((k >> 3) & 3) + (k & 3);
}

__device__ __forceinline__ unsigned int rne16(float w) {
  unsigned int b = __float_as_uint(w);
  return (b + 0x7FFFu + ((b >> 16) & 1u)) >> 16;
}

__device__ __forceinline__ bf16x8 pack8(f32x4 a, f32x4 b) {
  u32x4 u;
  u[0] = (__float_as_uint(a[1]) & 0xFFFF0000u) | (__float_as_uint(a[0]) >> 16);
  u[1] = (__float_as_uint(a[3]) & 0xFFFF0000u) | (__float_as_uint(a[2]) >> 16);
  u[2] = (__float_as_uint(b[1]) & 0xFFFF0000u) | (__float_as_uint(b[0]) >> 16);
  u[3] = (__float_as_uint(b[3]) & 0xFFFF0000u) | (__float_as_uint(b[2]) >> 16);
  return __builtin_bit_cast(bf16x8, u);
}

__device__ __forceinline__ void split8(f32x4 a, f32x4 b, bf16x8& hi, bf16x8& lo) {
  unsigned int h[4], l[4];
#pragma unroll
  for (int j = 0; j < 2; ++j) {
    unsigned int b0 = __float_as_uint(a[2 * j]);
    unsigned int b1 = __float_as_uint(a[2 * j + 1]);
    h[j] = (b1 & 0xFFFF0000u) | (b0 >> 16);
    float r0 = a[2 * j] - __uint_as_float(b0 & 0xFFFF0000u);
    float r1 = a[2 * j + 1] - __uint_as_float(b1 & 0xFFFF0000u);
    l[j] = (__float_as_uint(r1) & 0xFFFF0000u) | (__float_as_uint(r0) >> 16);
  }
#pragma unroll
  for (int j = 0; j < 2; ++j) {
    unsigned int b0 = __float_as_uint(b[2 * j]);
    unsigned int b1 = __float_as_uint(b[2 * j + 1]);
    h[2 + j] = (b1 & 0xFFFF0000u) | (b0 >> 16);
    float r0 = b[2 * j] - __uint_as_float(b0 & 0xFFFF0000u);
    float r1 = b[2 * j + 1] - __uint_as_float(b1 & 0xFFFF0000u);
    l[2 + j] = (__float_as_uint(r1) & 0xFFFF0000u) | (__float_as_uint(r0) >> 16);
  }
  u32x4 uh = {h[0], h[1], h[2], h[3]};
  u32x4 ul = {l[0], l[1], l[2], l[3]};
  hi = __builtin_bit_cast(bf16x8, uh);
  lo = __builtin_bit_cast(bf16x8, ul);
}

__device__ __forceinline__ f32x4 relu4(f32x4 a, f32x4 b) {
  f32x4 o;
#pragma unroll
  for (int j = 0; j < 4; ++j) o[j] = fmaxf(a[j] + b[j], 0.f);
  return o;
}

// ---------------------------------------------------------------------------
__global__ void k_init(float* __restrict__ ws) {
  int t = blockIdx.x * 256 + threadIdx.x;
  int stride = gridDim.x * 256;
  for (int i = t; i < 130 * NN; i += stride)
    ws[i] = (i >= NN && i < 2 * NN) ? 1.0f : 0.0f;
}

// ---------------------------------------------------------------------------
__global__ void k_scatter(const int* __restrict__ ei, const float* __restrict__ ea,
                          float* __restrict__ deg, float* __restrict__ dout,
                          float* __restrict__ sum_in, float* __restrict__ sum_src) {
  int t = blockIdx.x * 256 + threadIdx.x;
  if (t >= EE * 64) return;
  int e = t >> 6, f = t & 63;
  int s = ei[e];
  int d = ei[EE + e];
  float v = ea[t];
  atomicAdd(&sum_in[d * 64 + f], v);
  atomicAdd(&sum_src[s * 64 + f], v);
  if (f == 0) {
    atomicAdd(&deg[d], 1.0f);
    atomicAdd(&dout[s], 1.0f);
  }
}

// ---------------------------------------------------------------------------
// y: 0=Wnq 1=Wnk 2=Wnv 3=W4bot(PERMUTED) 4=W4top 5..14=Wsrc h=y-5,
// 15=W5(PERMUTED)+Cg/Cb. Cg/Cb sums over the cb bijection == true sums.
__global__ void k_prepall(const float* __restrict__ Wnq, const float* __restrict__ Wnk,
                          const float* __restrict__ Wnv, const float* __restrict__ W4,
                          const float* __restrict__ Wsrc, const float* __restrict__ W5,
                          const float* __restrict__ g1, const float* __restrict__ b1,
                          float* __restrict__ Cg, float* __restrict__ Cb,
                          unsigned short* __restrict__ wbuf) {
  const int c = blockIdx.x, f = threadIdx.x, y = blockIdx.y;
  if (y == 15) {
    const int cb = cbperm(f);
    float w = W5[cb * 64 + c];
    wbuf[OFF_W5T + c * 64 + f] = (unsigned short)rne16(w);
    float cg = g1[cb] * w;
    float cbb = b1[cb] * w;
#pragma unroll
    for (int off = 1; off < 64; off <<= 1) {
      cg += __shfl_xor(cg, off, 64);
      cbb += __shfl_xor(cbb, off, 64);
    }
    if (f == 0) {
      Cg[c] = cg;
      Cb[c] = cbb;
    }
    return;
  }
  float w;
  int hioff, looff = -1;
  const int cf = c * 64 + f;
  if (y == 0) { w = Wnq[f * 64 + c]; hioff = OFF_WNQ + cf; looff = OFF_WNQL + cf; }
  else if (y == 1) { w = Wnk[f * 64 + c]; hioff = OFF_WNK + cf; looff = OFF_WNKL + cf; }
  else if (y == 2) { w = Wnv[f * 64 + c]; hioff = OFF_WNV + cf; looff = OFF_WNVL + cf; }
  else if (y == 3) { w = W4[(64 + cbperm(f)) * 64 + c]; hioff = OFF_W4B + cf; }
  else if (y == 4) { w = W4[f * 64 + c]; hioff = OFF_W4T + cf; }
  else {
    int h = y - 5;
    w = Wsrc[f * 640 + h * 64 + c];
    hioff = OFF_WSRC + (h * 64 + c) * 64 + f;
    looff = OFF_WSRCL + (h * 64 + c) * 64 + f;
  }
  unsigned int hi = rne16(w);
  wbuf[hioff] = (unsigned short)hi;
  if (looff >= 0) {
    float rest = w - __uint_as_float(hi << 16);
    wbuf[looff] = (unsigned short)rne16(rest);
  }
}

// ---------------------------------------------------------------------------
// xsrc[(n*10+h)*64+c] = sum_f x[n][f]*Wsrc[f][h*64+c], 3-term hi/lo (fp32-level).
__global__ __launch_bounds__(256) void k_xsrcm(const float* __restrict__ x,
                                               const unsigned short* __restrict__ wbuf,
                                               float* __restrict__ xsrc) {
  const int lane = threadIdx.x & 63;
  const int wv = rfl((int)threadIdx.x >> 6);
  const int g = lane >> 4, r = lane & 15;
  const int h = blockIdx.y;
  const int n = (blockIdx.x * 4 + wv) * 16 + r;  // grid.x exact: NN/64
  bf16x8 whi[4][2], wlo[4][2];
#pragma unroll
  for (int mt = 0; mt < 4; ++mt)
#pragma unroll
    for (int ks = 0; ks < 2; ++ks) {
      const int off = (h * 64 + 16 * mt + r) * 64 + 32 * ks + 8 * g;
      whi[mt][ks] = *reinterpret_cast<const bf16x8*>(wbuf + OFF_WSRC + off);
      wlo[mt][ks] = *reinterpret_cast<const bf16x8*>(wbuf + OFF_WSRCL + off);
    }
  const float* xr = x + (size_t)n * 64 + 8 * g;
  bf16x8 xh0, xl0, xh1, xl1;
  split8(*reinterpret_cast<const f32x4*>(xr), *reinterpret_cast<const f32x4*>(xr + 4), xh0, xl0);
  split8(*reinterpret_cast<const f32x4*>(xr + 32), *reinterpret_cast<const f32x4*>(xr + 36), xh1, xl1);
  const size_t base = ((size_t)n * 10 + h) * 64;
#pragma unroll
  for (int mt = 0; mt < 4; ++mt) {
    f32x4 d = {0, 0, 0, 0};
    d = __builtin_amdgcn_mfma_f32_16x16x32_bf16(whi[mt][0], xh0, d, 0, 0, 0);
    d = __builtin_amdgcn_mfma_f32_16x16x32_bf16(whi[mt][1], xh1, d, 0, 0, 0);
    d = __builtin_amdgcn_mfma_f32_16x16x32_bf16(whi[mt][0], xl0, d, 0, 0, 0);
    d = __builtin_amdgcn_mfma_f32_16x16x32_bf16(whi[mt][1], xl1, d, 0, 0, 0);
    d = __builtin_amdgcn_mfma_f32_16x16x32_bf16(wlo[mt][0], xh0, d, 0, 0, 0);
    d = __builtin_amdgcn_mfma_f32_16x16x32_bf16(wlo[mt][1], xh1, d, 0, 0, 0);
    *reinterpret_cast<f32x4*>(xsrc + base + 16 * mt + 4 * g) = d;
  }
}

// ---------------------------------------------------------------------------
__global__ __launch_bounds__(256) void k_eaqkv(const float* __restrict__ deg,
                                               const float* __restrict__ sum_in,
                                               const float* __restrict__ sum_src,
                                               const float* __restrict__ Wek,
                                               const float* __restrict__ Weq,
                                               const float* __restrict__ Wev,
                                               float* __restrict__ eaQ,
                                               float* __restrict__ eaK,
                                               float* __restrict__ eaV) {
  const int lane = threadIdx.x & 63;
  const int wv = rfl(threadIdx.x >> 6);
  float wq[64], wk[64], wvv[64];
#pragma unroll
  for (int f = 0; f < 64; ++f) {
    wq[f] = Wek[f * 64 + lane];
    wk[f] = Weq[f * 64 + lane];
    wvv[f] = Wev[f * 64 + lane];
  }
  const int nw = gridDim.x * 4;
  for (int n = blockIdx.x * 4 + wv; n < NN; n += nw) {
    const float* si = sum_in + (size_t)n * 64;
    const float* ss = sum_src + (size_t)n * 64;
    const float invd = 1.0f / fmaxf(deg[n], 1.0f);
    float q0 = 0, q1 = 0, k0 = 0, k1 = 0, v0 = 0, v1 = 0;
#pragma unroll
    for (int f = 0; f < 64; f += 2) {
      float e0 = fmaf(si[f], invd, ss[f]);
      float e1 = fmaf(si[f + 1], invd, ss[f + 1]);
      q0 = fmaf(e0, wq[f], q0);
      q1 = fmaf(e1, wq[f + 1], q1);
      k0 = fmaf(e0, wk[f], k0);
      k1 = fmaf(e1, wk[f + 1], k1);
      v0 = fmaf(e0, wvv[f], v0);
      v1 = fmaf(e1, wvv[f + 1], v1);
    }
    eaQ[(size_t)n * 64 + lane] = q0 + q1;
    eaK[(size_t)n * 64 + lane] = k0 + k1;
    eaV[(size_t)n * 64 + lane] = v0 + v1;
  }
}

// ---------------------------------------------------------------------------
// qk via 3-term hi/lo MFMA projections + exact f32 eaQ/eaK + in-register dot.
__global__ __launch_bounds__(256) void k_qkm(const float* __restrict__ xsrc,
                                             const unsigned short* __restrict__ wbuf,
                                             const float* __restrict__ eaQ,
                                             const float* __restrict__ eaK,
                                             const float* __restrict__ dout,
                                             float* __restrict__ qk) {
  const int lane = threadIdx.x & 63;
  const int wv = rfl((int)threadIdx.x >> 6);
  const int g = lane >> 4, r = lane & 15;
  const int r0 = (blockIdx.x * 4 + wv) * 16;  // grid exact: NN*HH/64
  const int grow = r0 + r;
  const int n = grow / 10;
  const float* xp = xsrc + (size_t)grow * 64 + 8 * g;
  bf16x8 xh0, xl0, xh1, xl1;
  split8(*reinterpret_cast<const f32x4*>(xp), *reinterpret_cast<const f32x4*>(xp + 4), xh0, xl0);
  split8(*reinterpret_cast<const f32x4*>(xp + 32), *reinterpret_cast<const f32x4*>(xp + 36), xh1, xl1);
  const float dn = dout[n];
  f32x4 qf[4];
#pragma unroll
  for (int mt = 0; mt < 4; ++mt) {
    const int off = (16 * mt + r) * 64 + 8 * g;
    bf16x8 ah0 = *reinterpret_cast<const bf16x8*>(wbuf + OFF_WNQ + off);
    bf16x8 ah1 = *reinterpret_cast<const bf16x8*>(wbuf + OFF_WNQ + off + 32);
    bf16x8 al0 = *reinterpret_cast<const bf16x8*>(wbuf + OFF_WNQL + off);
    bf16x8 al1 = *reinterpret_cast<const bf16x8*>(wbuf + OFF_WNQL + off + 32);
    f32x4 d = {0, 0, 0, 0};
    d = __builtin_amdgcn_mfma_f32_16x16x32_bf16(ah0, xh0, d, 0, 0, 0);
    d = __builtin_amdgcn_mfma_f32_16x16x32_bf16(ah1, xh1, d, 0, 0, 0);
    d = __builtin_amdgcn_mfma_f32_16x16x32_bf16(ah0, xl0, d, 0, 0, 0);
    d = __builtin_amdgcn_mfma_f32_16x16x32_bf16(ah1, xl1, d, 0, 0, 0);
    d = __builtin_amdgcn_mfma_f32_16x16x32_bf16(al0, xh0, d, 0, 0, 0);
    d = __builtin_amdgcn_mfma_f32_16x16x32_bf16(al1, xh1, d, 0, 0, 0);
    qf[mt] = d;
  }
  float p = 0.f;
#pragma unroll
  for (int mt = 0; mt < 4; ++mt) {
    const int off = (16 * mt + r) * 64 + 8 * g;
    bf16x8 ah0 = *reinterpret_cast<const bf16x8*>(wbuf + OFF_WNK + off);
    bf16x8 ah1 = *reinterpret_cast<const bf16x8*>(wbuf + OFF_WNK + off + 32);
    bf16x8 al0 = *reinterpret_cast<const bf16x8*>(wbuf + OFF_WNKL + off);
    bf16x8 al1 = *reinterpret_cast<const bf16x8*>(wbuf + OFF_WNKL + off + 32);
    f32x4 d = {0, 0, 0, 0};
    d = __builtin_amdgcn_mfma_f32_16x16x32_bf16(ah0, xh0, d, 0, 0, 0);
    d = __builtin_amdgcn_mfma_f32_16x16x32_bf16(ah1, xh1, d, 0, 0, 0);
    d = __builtin_amdgcn_mfma_f32_16x16x32_bf16(ah0, xl0, d, 0, 0, 0);
    d = __builtin_amdgcn_mfma_f32_16x16x32_bf16(ah1, xl1, d, 0, 0, 0);
    d = __builtin_amdgcn_mfma_f32_16x16x32_bf16(al0, xh0, d, 0, 0, 0);
    d = __builtin_amdgcn_mfma_f32_16x16x32_bf16(al1, xh1, d, 0, 0, 0);
    f32x4 eq = *reinterpret_cast<const f32x4*>(eaQ + (size_t)n * 64 + 16 * mt + 4 * g);
    f32x4 ek = *reinterpret_cast<const f32x4*>(eaK + (size_t)n * 64 + 16 * mt + 4 * g);
#pragma unroll
    for (int q = 0; q < 4; ++q) p = fmaf(qf[mt][q] + eq[q], fmaf(dn, d[q], ek[q]), p);
  }
  p += __shfl_xor(p, 16, 64);
  p += __shfl_xor(p, 32, 64);
  if (lane < 16) qk[r0 + lane] = p * 0.125f;
}

// ---------------------------------------------------------------------------
__global__ void k_softmax(const float* __restrict__ qk, float* __restrict__ sm) {
  int n = blockIdx.x * 256 + threadIdx.x;
  if (n >= NN) return;
  float v[HH];
  float mx = -1e30f;
#pragma unroll
  for (int h = 0; h < HH; ++h) {
    v[h] = qk[n * HH + h];
    mx = fmaxf(mx, v[h]);
  }
  float s = 0;
#pragma unroll
  for (int h = 0; h < HH; ++h) {
    v[h] = expf(v[h] - mx);
    s += v[h];
  }
  float inv = 1.0f / s;
#pragma unroll
  for (int h = 0; h < HH; ++h) sm[n * HH + h] = v[h] * inv;
}

// ---------------------------------------------------------------------------
// V = dout*(xsrc@Wnv)+eaV (3-term); nu = xsrc*sm*V (f32); node_out = nu+bias;
// NB = nu @ W4bot -- nu packed DIRECTLY from C-layout, W4B is cb-permuted.
__global__ __launch_bounds__(256) void k_updm(const float* __restrict__ xsrc,
                                              const unsigned short* __restrict__ wbuf,
                                              const float* __restrict__ eaV,
                                              const float* __restrict__ dout,
                                              const float* __restrict__ sm,
                                              const float* __restrict__ bias,
                                              float* __restrict__ node_out,
                                              float* __restrict__ NB) {
  const int lane = threadIdx.x & 63;
  const int wv = rfl((int)threadIdx.x >> 6);
  const int g = lane >> 4, r = lane & 15;
  const int grow = (blockIdx.x * 4 + wv) * 16 + r;  // grid exact: NN*HH/64
  const int n = grow / 10;
  const int h = grow - 10 * n;
  const float* xp = xsrc + (size_t)grow * 64;
  bf16x8 xh0, xl0, xh1, xl1;
  split8(*reinterpret_cast<const f32x4*>(xp + 8 * g), *reinterpret_cast<const f32x4*>(xp + 8 * g + 4),
         xh0, xl0);
  split8(*reinterpret_cast<const f32x4*>(xp + 8 * g + 32),
         *reinterpret_cast<const f32x4*>(xp + 8 * g + 36), xh1, xl1);
  const float dn = dout[n];
  const float wgt = sm[grow];
  f32x4 nu[4];
#pragma unroll
  for (int mt = 0; mt < 4; ++mt) {
    const int off = (16 * mt + r) * 64 + 8 * g;
    bf16x8 ah0 = *reinterpret_cast<const bf16x8*>(wbuf + OFF_WNV + off);
    bf16x8 ah1 = *reinterpret_cast<const bf16x8*>(wbuf + OFF_WNV + off + 32);
    bf16x8 al0 = *reinterpret_cast<const bf16x8*>(wbuf + OFF_WNVL + off);
    bf16x8 al1 = *reinterpret_cast<const bf16x8*>(wbuf + OFF_WNVL + off + 32);
    f32x4 vf = {0, 0, 0, 0};
    vf = __builtin_amdgcn_mfma_f32_16x16x32_bf16(ah0, xh0, vf, 0, 0, 0);
    vf = __builtin_amdgcn_mfma_f32_16x16x32_bf16(ah1, xh1, vf, 0, 0, 0);
    vf = __builtin_amdgcn_mfma_f32_16x16x32_bf16(ah0, xl0, vf, 0, 0, 0);
    vf = __builtin_amdgcn_mfma_f32_16x16x32_bf16(ah1, xl1, vf, 0, 0, 0);
    vf = __builtin_amdgcn_mfma_f32_16x16x32_bf16(al0, xh0, vf, 0, 0, 0);
    vf = __builtin_amdgcn_mfma_f32_16x16x32_bf16(al1, xh1, vf, 0, 0, 0);
    f32x4 ev = *reinterpret_cast<const f32x4*>(eaV + (size_t)n * 64 + 16 * mt + 4 * g);
    f32x4 xs = *reinterpret_cast<const f32x4*>(xp + 16 * mt + 4 * g);
    f32x4 nn;
#pragma unroll
    for (int q = 0; q < 4; ++q) nn[q] = xs[q] * wgt * fmaf(dn, vf[q], ev[q]);
    nu[mt] = nn;
    f32x4 bs = *reinterpret_cast<const f32x4*>(bias + h * 64 + 16 * mt + 4 * g);
    *reinterpret_cast<f32x4*>(node_out + (size_t)grow * 64 + 16 * mt + 4 * g) = nn + bs;
  }
  // direct pack (cb-permutation replaces the exchange)
  bf16x8 nb0 = pack8(nu[0], nu[1]);
  bf16x8 nb1 = pack8(nu[2], nu[3]);
#pragma unroll
  for (int mt = 0; mt < 4; ++mt) {
    const int off = (16 * mt + r) * 64 + 8 * g;
    bf16x8 ba0 = *reinterpret_cast<const bf16x8*>(wbuf + OFF_W4B + off);
    bf16x8 ba1 = *reinterpret_cast<const bf16x8*>(wbuf + OFF_W4B + off + 32);
    f32x4 nf = {0, 0, 0, 0};
    nf = __builtin_amdgcn_mfma_f32_16x16x32_bf16(ba0, nb0, nf, 0, 0, 0);
    nf = __builtin_amdgcn_mfma_f32_16x16x32_bf16(ba1, nb1, nf, 0, 0, 0);
    *reinterpret_cast<f32x4*>(NB + (size_t)grow * 64 + 16 * mt + 4 * g) = nf;
  }
}

// ---------------------------------------------------------------------------
// Edge MLP v11: r13 structure + depth-1 prefetch of the nb gather (the
// measured per-head latency stall: src-indexed 256B-row gather from L2/L3).
__global__ __launch_bounds__(256) void k_edge8(
    const int* __restrict__ ei, const float* __restrict__ ea_g,
    const float* __restrict__ NB, const unsigned short* __restrict__ wbuf,
    const float* __restrict__ Cgp, const float* __restrict__ Cbp,
    const float* __restrict__ g1v, const float* __restrict__ g2v,
    const float* __restrict__ bias2, float* __restrict__ edge_out) {
  const int lane = threadIdx.x & 63;
  const int wv = rfl((int)threadIdx.x >> 6);
  const int g = lane >> 4;
  const int r = lane & 15;
  const int e = (blockIdx.x * 4 + wv) * 16 + r;
  const int src = ei[e];

  bf16x8 whi[4][2];  // cb-permuted W5T
#pragma unroll
  for (int mt = 0; mt < 4; ++mt)
#pragma unroll
    for (int ks = 0; ks < 2; ++ks)
      whi[mt][ks] = *reinterpret_cast<const bf16x8*>(wbuf + OFF_W5T + (16 * mt + r) * 64 +
                                                     32 * ks + 8 * g);

  const float* EAr = ea_g + (size_t)e * 64;
  const float* ear = EAr + 8 * g;

  // ---- fused A = ea @ W4top, KEPT in C-layout (feeds B1 via cb positions)
  f32x4 ad[4];
  {
    bf16x8 eb0 = pack8(*reinterpret_cast<const f32x4*>(ear),
                       *reinterpret_cast<const f32x4*>(ear + 4));
    bf16x8 eb1 = pack8(*reinterpret_cast<const f32x4*>(ear + 32),
                       *reinterpret_cast<const f32x4*>(ear + 36));
#pragma unroll
    for (int mt = 0; mt < 4; ++mt) {
      const int off = (16 * mt + r) * 64 + 8 * g;
      bf16x8 w0 = *reinterpret_cast<const bf16x8*>(wbuf + OFF_W4T + off);
      bf16x8 w1 = *reinterpret_cast<const bf16x8*>(wbuf + OFF_W4T + off + 32);
      f32x4 d = {0, 0, 0, 0};
      d = __builtin_amdgcn_mfma_f32_16x16x32_bf16(w0, eb0, d, 0, 0, 0);
      d = __builtin_amdgcn_mfma_f32_16x16x32_bf16(w1, eb1, d, 0, 0, 0);
      ad[mt] = d;
    }
  }

  const float* NBr = NB + (size_t)src * 640;
  f32x4 outacc[4] = {{0, 0, 0, 0}, {0, 0, 0, 0}, {0, 0, 0, 0}, {0, 0, 0, 0}};

  // prologue: load head 0's nb
  f32x4 c0 = *reinterpret_cast<const f32x4*>(NBr + 4 * g);
  f32x4 c1 = *reinterpret_cast<const f32x4*>(NBr + 16 + 4 * g);
  f32x4 c2 = *reinterpret_cast<const f32x4*>(NBr + 32 + 4 * g);
  f32x4 c3 = *reinterpret_cast<const f32x4*>(NBr + 48 + 4 * g);

#pragma unroll 1
  for (int h = 0; h < HH; ++h) {
    // ---- issue next head's gather FIRST (drains under this head's compute)
    f32x4 p0, p1, p2, p3;
    if (h < HH - 1) {
      const float* nbn = NBr + (h + 1) * 64;
      p0 = *reinterpret_cast<const f32x4*>(nbn + 4 * g);
      p1 = *reinterpret_cast<const f32x4*>(nbn + 16 + 4 * g);
      p2 = *reinterpret_cast<const f32x4*>(nbn + 32 + 4 * g);
      p3 = *reinterpret_cast<const f32x4*>(nbn + 48 + 4 * g);
    } else {
      p0 = p1 = p2 = p3 = (f32x4){0, 0, 0, 0};
    }

    bf16x8 bhi0 = pack8(relu4(ad[0], c0), relu4(ad[1], c1));
    bf16x8 bhi1 = pack8(relu4(ad[2], c2), relu4(ad[3], c3));

    f32x4 acc1[4];
#pragma unroll
    for (int mt = 0; mt < 4; ++mt) {
      f32x4 a = *reinterpret_cast<const f32x4*>(EAr + 16 * mt + 4 * g);
      a = __builtin_amdgcn_mfma_f32_16x16x32_bf16(whi[mt][0], bhi0, a, 0, 0, 0);
      a = __builtin_amdgcn_mfma_f32_16x16x32_bf16(whi[mt][1], bhi1, a, 0, 0, 0);
      acc1[mt] = a;
    }

    // LN1 stats for row r (lanes r, r+16, r+32, r+48)
    float s = 0.f, s2 = 0.f;
#pragma unroll
    for (int mt = 0; mt < 4; ++mt)
#pragma unroll
      for (int q = 0; q < 4; ++q) {
        float v = acc1[mt][q];
        s += v;
        s2 = fmaf(v, v, s2);
      }
    s += __shfl_xor(s, 16, 64);
    s2 += __shfl_xor(s2, 16, 64);
    s += __shfl_xor(s, 32, 64);
    s2 += __shfl_xor(s2, 32, 64);
    const float mu1 = s * 0.015625f;
    const float rs1 = rsqrtf(fmaxf(s2 * 0.015625f - mu1 * mu1, 1e-30f));

    // scale (true-index g1) and pack DIRECTLY (cb-permutation, no exchange)
#pragma unroll
    for (int mt = 0; mt < 4; ++mt) {
      f32x4 gv = *reinterpret_cast<const f32x4*>(g1v + 16 * mt + 4 * g);
      acc1[mt] = acc1[mt] * gv * rs1;
    }
    bf16x8 b20 = pack8(acc1[0], acc1[1]);
    bf16x8 b21 = pack8(acc1[2], acc1[3]);

    const float m1r1 = mu1 * rs1;
    f32x4 acc2[4];
#pragma unroll
    for (int mt = 0; mt < 4; ++mt) {
      f32x4 eav = *reinterpret_cast<const f32x4*>(EAr + 16 * mt + 4 * g);
      f32x4 cbv = *reinterpret_cast<const f32x4*>(Cbp + 16 * mt + 4 * g);
      f32x4 cgv = *reinterpret_cast<const f32x4*>(Cgp + 16 * mt + 4 * g);
      f32x4 a = eav + cbv - m1r1 * cgv;
      a = __builtin_amdgcn_mfma_f32_16x16x32_bf16(whi[mt][0], b20, a, 0, 0, 0);
      a = __builtin_amdgcn_mfma_f32_16x16x32_bf16(whi[mt][1], b21, a, 0, 0, 0);
      acc2[mt] = a;
    }

    float t = 0.f, t2 = 0.f;
#pragma unroll
    for (int mt = 0; mt < 4; ++mt)
#pragma unroll
      for (int q = 0; q < 4; ++q) {
        float v = acc2[mt][q];
        t += v;
        t2 = fmaf(v, v, t2);
      }
    t += __shfl_xor(t, 16, 64);
    t2 += __shfl_xor(t2, 16, 64);
    t += __shfl_xor(t, 32, 64);
    t2 += __shfl_xor(t2, 32, 64);
    const float mu2 = t * 0.015625f;
    const float rs2 = rsqrtf(fmaxf(t2 * 0.015625f - mu2 * mu2, 1e-30f));
#pragma unroll
    for (int mt = 0; mt < 4; ++mt) {
      f32x4 g2f = *reinterpret_cast<const f32x4*>(g2v + 16 * mt + 4 * g);
      f32x4 b2f = *reinterpret_cast<const f32x4*>(bias2 + 16 * mt + 4 * g);
      outacc[mt] += (acc2[mt] - mu2) * rs2 * g2f + b2f;
    }

    c0 = p0; c1 = p1; c2 = p2; c3 = p3;
  }

#pragma unroll
  for (int mt = 0; mt < 4; ++mt) {
    f32x4 o = outacc[mt] * 0.1f;
    *reinterpret_cast<f32x4*>(edge_out + (size_t)e * 64 + 16 * mt + 4 * g) = o;
  }
}

// ---------------------------------------------------------------------------
extern "C" void kernel_launch(void* const* d_in, const int* in_sizes, int n_in,
                              void* d_out, int out_size, void* d_ws, size_t ws_size,
                              hipStream_t stream) {
  const float* x = (const float*)d_in[0];
  const int* ei = (const int*)d_in[1];
  const float* edge_attr = (const float*)d_in[2];
  const float* W_src = (const float*)d_in[3];
  const float* Wnq = (const float*)d_in[4];
  const float* Wnk = (const float*)d_in[5];
  const float* Wnv = (const float*)d_in[6];
  const float* Weq = (const float*)d_in[7];
  const float* Wev = (const float*)d_in[8];
  const float* Wek = (const float*)d_in[9];
  const float* W4 = (const float*)d_in[10];
  const float* W5 = (const float*)d_in[11];
  const float* g1 = (const float*)d_in[12];
  const float* b1 = (const float*)d_in[13];
  const float* g2 = (const float*)d_in[14];
  const float* b2 = (const float*)d_in[15];
  const float* bias = (const float*)d_in[16];
  (void)in_sizes; (void)n_in; (void)out_size; (void)ws_size;

  float* ws = (float*)d_ws;
  float* deg = ws;
  float* dout = ws + NN;
  float* sum_in = ws + 2 * NN;
  float* sum_src = ws + 66 * NN;
  unsigned short* wbuf = (unsigned short*)(ws + 130 * NN);
  float* eaQ = ws + 194 * NN;
  float* eaK = ws + 258 * NN;
  float* eaV = ws + 322 * NN;
  float* xsrc = ws + 386 * NN;
  float* NB = ws + 1026 * NN;
  float* qk = ws + 1666 * NN;
  float* sm = ws + 1676 * NN;
  float* Cg = ws + 1686 * NN + 64 * EE;
  float* Cb = Cg + 64;

  float* node_out = (float*)d_out;
  float* edge_out = (float*)d_out + (size_t)NN * 640;

  k_init<<<1024, 256, 0, stream>>>(ws);
  k_prepall<<<dim3(64, 16), 64, 0, stream>>>(Wnq, Wnk, Wnv, W4, W_src, W5, g1, b1, Cg, Cb,
                                             wbuf);
  k_scatter<<<EE * 64 / 256, 256, 0, stream>>>(ei, edge_attr, deg, dout, sum_in, sum_src);
  k_xsrcm<<<dim3(NN / 64, 10), 256, 0, stream>>>(x, wbuf, xsrc);
  k_eaqkv<<<250, 256, 0, stream>>>(deg, sum_in, sum_src, Wek, Weq, Wev, eaQ, eaK, eaV);
  k_qkm<<<NN * HH / 64, 256, 0, stream>>>(xsrc, wbuf, eaQ, eaK, dout, qk);
  k_softmax<<<(NN + 255) / 256, 256, 0, stream>>>(qk, sm);
  k_updm<<<NN * HH / 64, 256, 0, stream>>>(xsrc, wbuf, eaV, dout, sm, bias, node_out, NB);
  k_edge8<<<EE / 64, 256, 0, stream>>>(ei, edge_attr, NB, wbuf, Cg, Cb, g1, g2, b2,
                                       edge_out);
}

// Round 15
// 172.024 us; speedup vs baseline: 1.0239x; 1.0239x over previous
//
#include <hip/hip_runtime.h>
#include <cstdint>
#include <cstddef>

#define NN 8000
#define EE 64000
#define HH 10

// wbuf (unsigned short) offsets
#define OFF_W5T 0      // PERMUTED: W5T[c'][k] = W5[cb(k)][c']
#define OFF_WNQ 4096
#define OFF_WNQL 8192
#define OFF_WNK 12288
#define OFF_WNKL 16384
#define OFF_WNV 20480
#define OFF_WNVL 24576
#define OFF_W4B 28672  // PERMUTED: W4B[c'][k] = W4[64+cb(k)][c']
#define OFF_W4T 32768
#define OFF_WSRC 36864
#define OFF_WSRCL 77824
#define OFF_WNQP 118784   // PERMUTED hi: Wnq[cb(k)][c']
#define OFF_WNQPL 122880  // PERMUTED lo
#define OFF_WNKP 126976
#define OFF_WNKPL 131072
// total 135168 shorts = 67584 floats (< 64*NN region)

typedef __attribute__((ext_vector_type(8))) short bf16x8;
typedef __attribute__((ext_vector_type(4))) float f32x4;
typedef __attribute__((ext_vector_type(4))) unsigned int u32x4;

__device__ __forceinline__ int rfl(int v) { return __builtin_amdgcn_readfirstlane(v); }

// Contraction-index permutation (r13-verified): position k (=32ks+8g+i) holds
// true channel cb(k) = 32ks + 16*(i>=4) + 4g + (i&3). C-layout regs pack
// DIRECTLY into B-frags when the weight array uses cb too.
__device__ __forceinline__ int cbperm(int k) {
  return 32 * (k >> 5) + 16 * ((k >> 2) & 1) + 4 * ((k >> 3) & 3) + (k & 3);
}

__device__ __forceinline__ unsigned int rne16(float w) {
  unsigned int b = __float_as_uint(w);
  return (b + 0x7FFFu + ((b >> 16) & 1u)) >> 16;
}

__device__ __forceinline__ bf16x8 pack8(f32x4 a, f32x4 b) {
  u32x4 u;
  u[0] = (__float_as_uint(a[1]) & 0xFFFF0000u) | (__float_as_uint(a[0]) >> 16);
  u[1] = (__float_as_uint(a[3]) & 0xFFFF0000u) | (__float_as_uint(a[2]) >> 16);
  u[2] = (__float_as_uint(b[1]) & 0xFFFF0000u) | (__float_as_uint(b[0]) >> 16);
  u[3] = (__float_as_uint(b[3]) & 0xFFFF0000u) | (__float_as_uint(b[2]) >> 16);
  return __builtin_bit_cast(bf16x8, u);
}

__device__ __forceinline__ void split8(f32x4 a, f32x4 b, bf16x8& hi, bf16x8& lo) {
  unsigned int h[4], l[4];
#pragma unroll
  for (int j = 0; j < 2; ++j) {
    unsigned int b0 = __float_as_uint(a[2 * j]);
    unsigned int b1 = __float_as_uint(a[2 * j + 1]);
    h[j] = (b1 & 0xFFFF0000u) | (b0 >> 16);
    float r0 = a[2 * j] - __uint_as_float(b0 & 0xFFFF0000u);
    float r1 = a[2 * j + 1] - __uint_as_float(b1 & 0xFFFF0000u);
    l[j] = (__float_as_uint(r1) & 0xFFFF0000u) | (__float_as_uint(r0) >> 16);
  }
#pragma unroll
  for (int j = 0; j < 2; ++j) {
    unsigned int b0 = __float_as_uint(b[2 * j]);
    unsigned int b1 = __float_as_uint(b[2 * j + 1]);
    h[2 + j] = (b1 & 0xFFFF0000u) | (b0 >> 16);
    float r0 = b[2 * j] - __uint_as_float(b0 & 0xFFFF0000u);
    float r1 = b[2 * j + 1] - __uint_as_float(b1 & 0xFFFF0000u);
    l[2 + j] = (__float_as_uint(r1) & 0xFFFF0000u) | (__float_as_uint(r0) >> 16);
  }
  u32x4 uh = {h[0], h[1], h[2], h[3]};
  u32x4 ul = {l[0], l[1], l[2], l[3]};
  hi = __builtin_bit_cast(bf16x8, uh);
  lo = __builtin_bit_cast(bf16x8, ul);
}

__device__ __forceinline__ f32x4 relu4(f32x4 a, f32x4 b) {
  f32x4 o;
#pragma unroll
  for (int j = 0; j < 4; ++j) o[j] = fmaxf(a[j] + b[j], 0.f);
  return o;
}

// ---------------------------------------------------------------------------
__global__ void k_init(float* __restrict__ ws) {
  int t = blockIdx.x * 256 + threadIdx.x;
  int stride = gridDim.x * 256;
  for (int i = t; i < 130 * NN; i += stride)
    ws[i] = (i >= NN && i < 2 * NN) ? 1.0f : 0.0f;
}

// ---------------------------------------------------------------------------
__global__ void k_scatter(const int* __restrict__ ei, const float* __restrict__ ea,
                          float* __restrict__ deg, float* __restrict__ dout,
                          float* __restrict__ sum_in, float* __restrict__ sum_src) {
  int t = blockIdx.x * 256 + threadIdx.x;
  if (t >= EE * 64) return;
  int e = t >> 6, f = t & 63;
  int s = ei[e];
  int d = ei[EE + e];
  float v = ea[t];
  atomicAdd(&sum_in[d * 64 + f], v);
  atomicAdd(&sum_src[s * 64 + f], v);
  if (f == 0) {
    atomicAdd(&deg[d], 1.0f);
    atomicAdd(&dout[s], 1.0f);
  }
}

// ---------------------------------------------------------------------------
// y: 0=Wnq 1=Wnk 2=Wnv 3=W4bot(P) 4=W4top 5..14=Wsrc h=y-5, 15=W5(P)+Cg/Cb,
// 16=Wnq(P hi/lo), 17=Wnk(P hi/lo).
__global__ void k_prepall(const float* __restrict__ Wnq, const float* __restrict__ Wnk,
                          const float* __restrict__ Wnv, const float* __restrict__ W4,
                          const float* __restrict__ Wsrc, const float* __restrict__ W5,
                          const float* __restrict__ g1, const float* __restrict__ b1,
                          float* __restrict__ Cg, float* __restrict__ Cb,
                          unsigned short* __restrict__ wbuf) {
  const int c = blockIdx.x, f = threadIdx.x, y = blockIdx.y;
  if (y == 15) {
    const int cb = cbperm(f);
    float w = W5[cb * 64 + c];
    wbuf[OFF_W5T + c * 64 + f] = (unsigned short)rne16(w);
    float cg = g1[cb] * w;
    float cbb = b1[cb] * w;
#pragma unroll
    for (int off = 1; off < 64; off <<= 1) {
      cg += __shfl_xor(cg, off, 64);
      cbb += __shfl_xor(cbb, off, 64);
    }
    if (f == 0) {
      Cg[c] = cg;
      Cb[c] = cbb;
    }
    return;
  }
  float w;
  int hioff, looff = -1;
  const int cf = c * 64 + f;
  if (y == 0) { w = Wnq[f * 64 + c]; hioff = OFF_WNQ + cf; looff = OFF_WNQL + cf; }
  else if (y == 1) { w = Wnk[f * 64 + c]; hioff = OFF_WNK + cf; looff = OFF_WNKL + cf; }
  else if (y == 2) { w = Wnv[f * 64 + c]; hioff = OFF_WNV + cf; looff = OFF_WNVL + cf; }
  else if (y == 3) { w = W4[(64 + cbperm(f)) * 64 + c]; hioff = OFF_W4B + cf; }
  else if (y == 4) { w = W4[f * 64 + c]; hioff = OFF_W4T + cf; }
  else if (y == 16) { w = Wnq[cbperm(f) * 64 + c]; hioff = OFF_WNQP + cf; looff = OFF_WNQPL + cf; }
  else if (y == 17) { w = Wnk[cbperm(f) * 64 + c]; hioff = OFF_WNKP + cf; looff = OFF_WNKPL + cf; }
  else {
    int h = y - 5;
    w = Wsrc[f * 640 + h * 64 + c];
    hioff = OFF_WSRC + (h * 64 + c) * 64 + f;
    looff = OFF_WSRCL + (h * 64 + c) * 64 + f;
  }
  unsigned int hi = rne16(w);
  wbuf[hioff] = (unsigned short)hi;
  if (looff >= 0) {
    float rest = w - __uint_as_float(hi << 16);
    wbuf[looff] = (unsigned short)rne16(rest);
  }
}

// ---------------------------------------------------------------------------
// Fused xsrc + qk: per wave = 16 nodes, fixed head h.
// xsrc row (3-term hi/lo, f-layout weights) -> stored f32 AND kept in C-layout
// regs; Q/K projections use cb-permuted Wnq/Wnk on the C-layout regs directly
// (r13 cb trick), then in-register dot + 2-shuffle reduce -> qk.
__global__ __launch_bounds__(256) void k_xsrcq(const float* __restrict__ x,
                                               const unsigned short* __restrict__ wbuf,
                                               const float* __restrict__ eaQ,
                                               const float* __restrict__ eaK,
                                               const float* __restrict__ dout,
                                               float* __restrict__ xsrc,
                                               float* __restrict__ qk) {
  const int lane = threadIdx.x & 63;
  const int wv = rfl((int)threadIdx.x >> 6);
  const int g = lane >> 4, r = lane & 15;
  const int h = blockIdx.y;
  const int n0 = (blockIdx.x * 4 + wv) * 16;  // grid.x exact: NN/64
  const int n = n0 + r;
  bf16x8 whi[4][2], wlo[4][2];
#pragma unroll
  for (int mt = 0; mt < 4; ++mt)
#pragma unroll
    for (int ks = 0; ks < 2; ++ks) {
      const int off = (h * 64 + 16 * mt + r) * 64 + 32 * ks + 8 * g;
      whi[mt][ks] = *reinterpret_cast<const bf16x8*>(wbuf + OFF_WSRC + off);
      wlo[mt][ks] = *reinterpret_cast<const bf16x8*>(wbuf + OFF_WSRCL + off);
    }
  const float* xr = x + (size_t)n * 64 + 8 * g;
  bf16x8 xh0, xl0, xh1, xl1;
  split8(*reinterpret_cast<const f32x4*>(xr), *reinterpret_cast<const f32x4*>(xr + 4), xh0, xl0);
  split8(*reinterpret_cast<const f32x4*>(xr + 32), *reinterpret_cast<const f32x4*>(xr + 36), xh1, xl1);
  const size_t base = ((size_t)n * 10 + h) * 64;
  f32x4 d[4];
#pragma unroll
  for (int mt = 0; mt < 4; ++mt) {
    f32x4 a = {0, 0, 0, 0};
    a = __builtin_amdgcn_mfma_f32_16x16x32_bf16(whi[mt][0], xh0, a, 0, 0, 0);
    a = __builtin_amdgcn_mfma_f32_16x16x32_bf16(whi[mt][1], xh1, a, 0, 0, 0);
    a = __builtin_amdgcn_mfma_f32_16x16x32_bf16(whi[mt][0], xl0, a, 0, 0, 0);
    a = __builtin_amdgcn_mfma_f32_16x16x32_bf16(whi[mt][1], xl1, a, 0, 0, 0);
    a = __builtin_amdgcn_mfma_f32_16x16x32_bf16(wlo[mt][0], xh0, a, 0, 0, 0);
    a = __builtin_amdgcn_mfma_f32_16x16x32_bf16(wlo[mt][1], xh1, a, 0, 0, 0);
    d[mt] = a;
    *reinterpret_cast<f32x4*>(xsrc + base + 16 * mt + 4 * g) = a;
  }
  // ---- Q/K projections: d (C-layout) -> B-frags via cb positions
  bf16x8 dh0, dl0, dh1, dl1;
  split8(d[0], d[1], dh0, dl0);
  split8(d[2], d[3], dh1, dl1);
  const float dn = dout[n];
  f32x4 qf[4];
#pragma unroll
  for (int mt = 0; mt < 4; ++mt) {
    const int off = (16 * mt + r) * 64 + 8 * g;
    bf16x8 ah0 = *reinterpret_cast<const bf16x8*>(wbuf + OFF_WNQP + off);
    bf16x8 ah1 = *reinterpret_cast<const bf16x8*>(wbuf + OFF_WNQP + off + 32);
    bf16x8 al0 = *reinterpret_cast<const bf16x8*>(wbuf + OFF_WNQPL + off);
    bf16x8 al1 = *reinterpret_cast<const bf16x8*>(wbuf + OFF_WNQPL + off + 32);
    f32x4 a = {0, 0, 0, 0};
    a = __builtin_amdgcn_mfma_f32_16x16x32_bf16(ah0, dh0, a, 0, 0, 0);
    a = __builtin_amdgcn_mfma_f32_16x16x32_bf16(ah1, dh1, a, 0, 0, 0);
    a = __builtin_amdgcn_mfma_f32_16x16x32_bf16(ah0, dl0, a, 0, 0, 0);
    a = __builtin_amdgcn_mfma_f32_16x16x32_bf16(ah1, dl1, a, 0, 0, 0);
    a = __builtin_amdgcn_mfma_f32_16x16x32_bf16(al0, dh0, a, 0, 0, 0);
    a = __builtin_amdgcn_mfma_f32_16x16x32_bf16(al1, dh1, a, 0, 0, 0);
    qf[mt] = a;
  }
  float p = 0.f;
#pragma unroll
  for (int mt = 0; mt < 4; ++mt) {
    const int off = (16 * mt + r) * 64 + 8 * g;
    bf16x8 ah0 = *reinterpret_cast<const bf16x8*>(wbuf + OFF_WNKP + off);
    bf16x8 ah1 = *reinterpret_cast<const bf16x8*>(wbuf + OFF_WNKP + off + 32);
    bf16x8 al0 = *reinterpret_cast<const bf16x8*>(wbuf + OFF_WNKPL + off);
    bf16x8 al1 = *reinterpret_cast<const bf16x8*>(wbuf + OFF_WNKPL + off + 32);
    f32x4 a = {0, 0, 0, 0};
    a = __builtin_amdgcn_mfma_f32_16x16x32_bf16(ah0, dh0, a, 0, 0, 0);
    a = __builtin_amdgcn_mfma_f32_16x16x32_bf16(ah1, dh1, a, 0, 0, 0);
    a = __builtin_amdgcn_mfma_f32_16x16x32_bf16(ah0, dl0, a, 0, 0, 0);
    a = __builtin_amdgcn_mfma_f32_16x16x32_bf16(ah1, dl1, a, 0, 0, 0);
    a = __builtin_amdgcn_mfma_f32_16x16x32_bf16(al0, dh0, a, 0, 0, 0);
    a = __builtin_amdgcn_mfma_f32_16x16x32_bf16(al1, dh1, a, 0, 0, 0);
    f32x4 eq = *reinterpret_cast<const f32x4*>(eaQ + (size_t)n * 64 + 16 * mt + 4 * g);
    f32x4 ek = *reinterpret_cast<const f32x4*>(eaK + (size_t)n * 64 + 16 * mt + 4 * g);
#pragma unroll
    for (int q = 0; q < 4; ++q) p = fmaf(qf[mt][q] + eq[q], fmaf(dn, a[q], ek[q]), p);
  }
  p += __shfl_xor(p, 16, 64);
  p += __shfl_xor(p, 32, 64);
  if (lane < 16) qk[(size_t)(n0 + lane) * HH + h] = p * 0.125f;
}

// ---------------------------------------------------------------------------
__global__ __launch_bounds__(256) void k_eaqkv(const float* __restrict__ deg,
                                               const float* __restrict__ sum_in,
                                               const float* __restrict__ sum_src,
                                               const float* __restrict__ Wek,
                                               const float* __restrict__ Weq,
                                               const float* __restrict__ Wev,
                                               float* __restrict__ eaQ,
                                               float* __restrict__ eaK,
                                               float* __restrict__ eaV) {
  const int lane = threadIdx.x & 63;
  const int wv = rfl(threadIdx.x >> 6);
  float wq[64], wk[64], wvv[64];
#pragma unroll
  for (int f = 0; f < 64; ++f) {
    wq[f] = Wek[f * 64 + lane];
    wk[f] = Weq[f * 64 + lane];
    wvv[f] = Wev[f * 64 + lane];
  }
  const int nw = gridDim.x * 4;
  for (int n = blockIdx.x * 4 + wv; n < NN; n += nw) {
    const float* si = sum_in + (size_t)n * 64;
    const float* ss = sum_src + (size_t)n * 64;
    const float invd = 1.0f / fmaxf(deg[n], 1.0f);
    float q0 = 0, q1 = 0, k0 = 0, k1 = 0, v0 = 0, v1 = 0;
#pragma unroll
    for (int f = 0; f < 64; f += 2) {
      float e0 = fmaf(si[f], invd, ss[f]);
      float e1 = fmaf(si[f + 1], invd, ss[f + 1]);
      q0 = fmaf(e0, wq[f], q0);
      q1 = fmaf(e1, wq[f + 1], q1);
      k0 = fmaf(e0, wk[f], k0);
      k1 = fmaf(e1, wk[f + 1], k1);
      v0 = fmaf(e0, wvv[f], v0);
      v1 = fmaf(e1, wvv[f + 1], v1);
    }
    eaQ[(size_t)n * 64 + lane] = q0 + q1;
    eaK[(size_t)n * 64 + lane] = k0 + k1;
    eaV[(size_t)n * 64 + lane] = v0 + v1;
  }
}

// ---------------------------------------------------------------------------
__global__ void k_softmax(const float* __restrict__ qk, float* __restrict__ sm) {
  int n = blockIdx.x * 256 + threadIdx.x;
  if (n >= NN) return;
  float v[HH];
  float mx = -1e30f;
#pragma unroll
  for (int h = 0; h < HH; ++h) {
    v[h] = qk[n * HH + h];
    mx = fmaxf(mx, v[h]);
  }
  float s = 0;
#pragma unroll
  for (int h = 0; h < HH; ++h) {
    v[h] = expf(v[h] - mx);
    s += v[h];
  }
  float inv = 1.0f / s;
#pragma unroll
  for (int h = 0; h < HH; ++h) sm[n * HH + h] = v[h] * inv;
}

// ---------------------------------------------------------------------------
// V = dout*(xsrc@Wnv)+eaV (3-term); nu = xsrc*sm*V (f32); node_out = nu+bias;
// NB = nu @ W4bot -- direct pack (cb-permuted W4B).
__global__ __launch_bounds__(256) void k_updm(const float* __restrict__ xsrc,
                                              const unsigned short* __restrict__ wbuf,
                                              const float* __restrict__ eaV,
                                              const float* __restrict__ dout,
                                              const float* __restrict__ sm,
                                              const float* __restrict__ bias,
                                              float* __restrict__ node_out,
                                              float* __restrict__ NB) {
  const int lane = threadIdx.x & 63;
  const int wv = rfl((int)threadIdx.x >> 6);
  const int g = lane >> 4, r = lane & 15;
  const int grow = (blockIdx.x * 4 + wv) * 16 + r;  // grid exact: NN*HH/64
  const int n = grow / 10;
  const int h = grow - 10 * n;
  const float* xp = xsrc + (size_t)grow * 64;
  bf16x8 xh0, xl0, xh1, xl1;
  split8(*reinterpret_cast<const f32x4*>(xp + 8 * g), *reinterpret_cast<const f32x4*>(xp + 8 * g + 4),
         xh0, xl0);
  split8(*reinterpret_cast<const f32x4*>(xp + 8 * g + 32),
         *reinterpret_cast<const f32x4*>(xp + 8 * g + 36), xh1, xl1);
  const float dn = dout[n];
  const float wgt = sm[grow];
  f32x4 nu[4];
#pragma unroll
  for (int mt = 0; mt < 4; ++mt) {
    const int off = (16 * mt + r) * 64 + 8 * g;
    bf16x8 ah0 = *reinterpret_cast<const bf16x8*>(wbuf + OFF_WNV + off);
    bf16x8 ah1 = *reinterpret_cast<const bf16x8*>(wbuf + OFF_WNV + off + 32);
    bf16x8 al0 = *reinterpret_cast<const bf16x8*>(wbuf + OFF_WNVL + off);
    bf16x8 al1 = *reinterpret_cast<const bf16x8*>(wbuf + OFF_WNVL + off + 32);
    f32x4 vf = {0, 0, 0, 0};
    vf = __builtin_amdgcn_mfma_f32_16x16x32_bf16(ah0, xh0, vf, 0, 0, 0);
    vf = __builtin_amdgcn_mfma_f32_16x16x32_bf16(ah1, xh1, vf, 0, 0, 0);
    vf = __builtin_amdgcn_mfma_f32_16x16x32_bf16(ah0, xl0, vf, 0, 0, 0);
    vf = __builtin_amdgcn_mfma_f32_16x16x32_bf16(ah1, xl1, vf, 0, 0, 0);
    vf = __builtin_amdgcn_mfma_f32_16x16x32_bf16(al0, xh0, vf, 0, 0, 0);
    vf = __builtin_amdgcn_mfma_f32_16x16x32_bf16(al1, xh1, vf, 0, 0, 0);
    f32x4 ev = *reinterpret_cast<const f32x4*>(eaV + (size_t)n * 64 + 16 * mt + 4 * g);
    f32x4 xs = *reinterpret_cast<const f32x4*>(xp + 16 * mt + 4 * g);
    f32x4 nn;
#pragma unroll
    for (int q = 0; q < 4; ++q) nn[q] = xs[q] * wgt * fmaf(dn, vf[q], ev[q]);
    nu[mt] = nn;
    f32x4 bs = *reinterpret_cast<const f32x4*>(bias + h * 64 + 16 * mt + 4 * g);
    *reinterpret_cast<f32x4*>(node_out + (size_t)grow * 64 + 16 * mt + 4 * g) = nn + bs;
  }
  bf16x8 nb0 = pack8(nu[0], nu[1]);
  bf16x8 nb1 = pack8(nu[2], nu[3]);
#pragma unroll
  for (int mt = 0; mt < 4; ++mt) {
    const int off = (16 * mt + r) * 64 + 8 * g;
    bf16x8 ba0 = *reinterpret_cast<const bf16x8*>(wbuf + OFF_W4B + off);
    bf16x8 ba1 = *reinterpret_cast<const bf16x8*>(wbuf + OFF_W4B + off + 32);
    f32x4 nf = {0, 0, 0, 0};
    nf = __builtin_amdgcn_mfma_f32_16x16x32_bf16(ba0, nb0, nf, 0, 0, 0);
    nf = __builtin_amdgcn_mfma_f32_16x16x32_bf16(ba1, nb1, nf, 0, 0, 0);
    *reinterpret_cast<f32x4*>(NB + (size_t)grow * 64 + 16 * mt + 4 * g) = nf;
  }
}

// ---------------------------------------------------------------------------
// Edge MLP v12: r13 structure + ALL loop-invariants hoisted into registers
// (the measured per-head stall: ~24 re-loads/head at VGPR=112). launch_bounds
// (256,2) raises the allocator cap to 256 VGPR; live set ~210, no spill.
__global__ __launch_bounds__(256, 2) void k_edge9(
    const int* __restrict__ ei, const float* __restrict__ ea_g,
    const float* __restrict__ NB, const unsigned short* __restrict__ wbuf,
    const float* __restrict__ Cgp, const float* __restrict__ Cbp,
    const float* __restrict__ g1v, const float* __restrict__ g2v,
    const float* __restrict__ bias2, float* __restrict__ edge_out) {
  const int lane = threadIdx.x & 63;
  const int wv = rfl((int)threadIdx.x >> 6);
  const int g = lane >> 4;
  const int r = lane & 15;
  const int e = (blockIdx.x * 4 + wv) * 16 + r;
  const int src = ei[e];

  bf16x8 whi[4][2];  // cb-permuted W5T
#pragma unroll
  for (int mt = 0; mt < 4; ++mt)
#pragma unroll
    for (int ks = 0; ks < 2; ++ks)
      whi[mt][ks] = *reinterpret_cast<const bf16x8*>(wbuf + OFF_W5T + (16 * mt + r) * 64 +
                                                     32 * ks + 8 * g);

  const float* EAr = ea_g + (size_t)e * 64;
  const float* ear = EAr + 8 * g;

  // ---- hoisted loop invariants (C-layout, 96 VGPRs)
  f32x4 eav[4], cbv[4], cgv[4], g1r[4], g2r[4], b2r[4];
#pragma unroll
  for (int mt = 0; mt < 4; ++mt) {
    eav[mt] = *reinterpret_cast<const f32x4*>(EAr + 16 * mt + 4 * g);
    cbv[mt] = *reinterpret_cast<const f32x4*>(Cbp + 16 * mt + 4 * g);
    cgv[mt] = *reinterpret_cast<const f32x4*>(Cgp + 16 * mt + 4 * g);
    g1r[mt] = *reinterpret_cast<const f32x4*>(g1v + 16 * mt + 4 * g);
    g2r[mt] = *reinterpret_cast<const f32x4*>(g2v + 16 * mt + 4 * g);
    b2r[mt] = *reinterpret_cast<const f32x4*>(bias2 + 16 * mt + 4 * g);
  }

  // ---- fused A = ea @ W4top, KEPT in C-layout (feeds B1 via cb positions)
  f32x4 ad[4];
  {
    bf16x8 eb0 = pack8(*reinterpret_cast<const f32x4*>(ear),
                       *reinterpret_cast<const f32x4*>(ear + 4));
    bf16x8 eb1 = pack8(*reinterpret_cast<const f32x4*>(ear + 32),
                       *reinterpret_cast<const f32x4*>(ear + 36));
#pragma unroll
    for (int mt = 0; mt < 4; ++mt) {
      const int off = (16 * mt + r) * 64 + 8 * g;
      bf16x8 w0 = *reinterpret_cast<const bf16x8*>(wbuf + OFF_W4T + off);
      bf16x8 w1 = *reinterpret_cast<const bf16x8*>(wbuf + OFF_W4T + off + 32);
      f32x4 d = {0, 0, 0, 0};
      d = __builtin_amdgcn_mfma_f32_16x16x32_bf16(w0, eb0, d, 0, 0, 0);
      d = __builtin_amdgcn_mfma_f32_16x16x32_bf16(w1, eb1, d, 0, 0, 0);
      ad[mt] = d;
    }
  }

  const float* NBr = NB + (size_t)src * 640;
  f32x4 outacc[4] = {{0, 0, 0, 0}, {0, 0, 0, 0}, {0, 0, 0, 0}, {0, 0, 0, 0}};

  // prologue: load head 0's nb
  f32x4 c0 = *reinterpret_cast<const f32x4*>(NBr + 4 * g);
  f32x4 c1 = *reinterpret_cast<const f32x4*>(NBr + 16 + 4 * g);
  f32x4 c2 = *reinterpret_cast<const f32x4*>(NBr + 32 + 4 * g);
  f32x4 c3 = *reinterpret_cast<const f32x4*>(NBr + 48 + 4 * g);

#pragma unroll 1
  for (int h = 0; h < HH; ++h) {
    // issue next head's gather first (drains under this head's compute)
    f32x4 p0, p1, p2, p3;
    if (h < HH - 1) {
      const float* nbn = NBr + (h + 1) * 64;
      p0 = *reinterpret_cast<const f32x4*>(nbn + 4 * g);
      p1 = *reinterpret_cast<const f32x4*>(nbn + 16 + 4 * g);
      p2 = *reinterpret_cast<const f32x4*>(nbn + 32 + 4 * g);
      p3 = *reinterpret_cast<const f32x4*>(nbn + 48 + 4 * g);
    } else {
      p0 = p1 = p2 = p3 = (f32x4){0, 0, 0, 0};
    }

    bf16x8 bhi0 = pack8(relu4(ad[0], c0), relu4(ad[1], c1));
    bf16x8 bhi1 = pack8(relu4(ad[2], c2), relu4(ad[3], c3));

    f32x4 acc1[4];
#pragma unroll
    for (int mt = 0; mt < 4; ++mt) {
      f32x4 a = eav[mt];
      a = __builtin_amdgcn_mfma_f32_16x16x32_bf16(whi[mt][0], bhi0, a, 0, 0, 0);
      a = __builtin_amdgcn_mfma_f32_16x16x32_bf16(whi[mt][1], bhi1, a, 0, 0, 0);
      acc1[mt] = a;
    }

    float s = 0.f, s2 = 0.f;
#pragma unroll
    for (int mt = 0; mt < 4; ++mt)
#pragma unroll
      for (int q = 0; q < 4; ++q) {
        float v = acc1[mt][q];
        s += v;
        s2 = fmaf(v, v, s2);
      }
    s += __shfl_xor(s, 16, 64);
    s2 += __shfl_xor(s2, 16, 64);
    s += __shfl_xor(s, 32, 64);
    s2 += __shfl_xor(s2, 32, 64);
    const float mu1 = s * 0.015625f;
    const float rs1 = rsqrtf(fmaxf(s2 * 0.015625f - mu1 * mu1, 1e-30f));

#pragma unroll
    for (int mt = 0; mt < 4; ++mt) acc1[mt] = acc1[mt] * g1r[mt] * rs1;
    bf16x8 b20 = pack8(acc1[0], acc1[1]);
    bf16x8 b21 = pack8(acc1[2], acc1[3]);

    const float m1r1 = mu1 * rs1;
    f32x4 acc2[4];
#pragma unroll
    for (int mt = 0; mt < 4; ++mt) {
      f32x4 a = eav[mt] + cbv[mt] - m1r1 * cgv[mt];
      a = __builtin_amdgcn_mfma_f32_16x16x32_bf16(whi[mt][0], b20, a, 0, 0, 0);
      a = __builtin_amdgcn_mfma_f32_16x16x32_bf16(whi[mt][1], b21, a, 0, 0, 0);
      acc2[mt] = a;
    }

    float t = 0.f, t2 = 0.f;
#pragma unroll
    for (int mt = 0; mt < 4; ++mt)
#pragma unroll
      for (int q = 0; q < 4; ++q) {
        float v = acc2[mt][q];
        t += v;
        t2 = fmaf(v, v, t2);
      }
    t += __shfl_xor(t, 16, 64);
    t2 += __shfl_xor(t2, 16, 64);
    t += __shfl_xor(t, 32, 64);
    t2 += __shfl_xor(t2, 32, 64);
    const float mu2 = t * 0.015625f;
    const float rs2 = rsqrtf(fmaxf(t2 * 0.015625f - mu2 * mu2, 1e-30f));
#pragma unroll
    for (int mt = 0; mt < 4; ++mt)
      outacc[mt] += (acc2[mt] - mu2) * rs2 * g2r[mt] + b2r[mt];

    c0 = p0; c1 = p1; c2 = p2; c3 = p3;
  }

#pragma unroll
  for (int mt = 0; mt < 4; ++mt) {
    f32x4 o = outacc[mt] * 0.1f;
    *reinterpret_cast<f32x4*>(edge_out + (size_t)e * 64 + 16 * mt + 4 * g) = o;
  }
}

// ---------------------------------------------------------------------------
extern "C" void kernel_launch(void* const* d_in, const int* in_sizes, int n_in,
                              void* d_out, int out_size, void* d_ws, size_t ws_size,
                              hipStream_t stream) {
  const float* x = (const float*)d_in[0];
  const int* ei = (const int*)d_in[1];
  const float* edge_attr = (const float*)d_in[2];
  const float* W_src = (const float*)d_in[3];
  const float* Wnq = (const float*)d_in[4];
  const float* Wnk = (const float*)d_in[5];
  const float* Wnv = (const float*)d_in[6];
  const float* Weq = (const float*)d_in[7];
  const float* Wev = (const float*)d_in[8];
  const float* Wek = (const float*)d_in[9];
  const float* W4 = (const float*)d_in[10];
  const float* W5 = (const float*)d_in[11];
  const float* g1 = (const float*)d_in[12];
  const float* b1 = (const float*)d_in[13];
  const float* g2 = (const float*)d_in[14];
  const float* b2 = (const float*)d_in[15];
  const float* bias = (const float*)d_in[16];
  (void)in_sizes; (void)n_in; (void)out_size; (void)ws_size;

  float* ws = (float*)d_ws;
  float* deg = ws;
  float* dout = ws + NN;
  float* sum_in = ws + 2 * NN;
  float* sum_src = ws + 66 * NN;
  unsigned short* wbuf = (unsigned short*)(ws + 130 * NN);
  float* eaQ = ws + 194 * NN;
  float* eaK = ws + 258 * NN;
  float* eaV = ws + 322 * NN;
  float* xsrc = ws + 386 * NN;
  float* NB = ws + 1026 * NN;
  float* qk = ws + 1666 * NN;
  float* sm = ws + 1676 * NN;
  float* Cg = ws + 1686 * NN + 64 * EE;
  float* Cb = Cg + 64;

  float* node_out = (float*)d_out;
  float* edge_out = (float*)d_out + (size_t)NN * 640;

  k_init<<<1024, 256, 0, stream>>>(ws);
  k_prepall<<<dim3(64, 18), 64, 0, stream>>>(Wnq, Wnk, Wnv, W4, W_src, W5, g1, b1, Cg, Cb,
                                             wbuf);
  k_scatter<<<EE * 64 / 256, 256, 0, stream>>>(ei, edge_attr, deg, dout, sum_in, sum_src);
  k_eaqkv<<<250, 256, 0, stream>>>(deg, sum_in, sum_src, Wek, Weq, Wev, eaQ, eaK, eaV);
  k_xsrcq<<<dim3(NN / 64, 10), 256, 0, stream>>>(x, wbuf, eaQ, eaK, dout, xsrc, qk);
  k_softmax<<<(NN + 255) / 256, 256, 0, stream>>>(qk, sm);
  k_updm<<<NN * HH / 64, 256, 0, stream>>>(xsrc, wbuf, eaV, dout, sm, bias, node_out, NB);
  k_edge9<<<EE / 64, 256, 0, stream>>>(ei, edge_attr, NB, wbuf, Cg, Cb, g1, g2, b2,
                                       edge_out);
}

// Round 16
// 170.294 us; speedup vs baseline: 1.0343x; 1.0102x over previous
//
#include <hip/hip_runtime.h>
#include <cstdint>
#include <cstddef>

#define NN 8000
#define EE 64000
#define HH 10

// wbuf (unsigned short) offsets
#define OFF_W5T 0      // PERMUTED: W5T[c'][k] = W5[cb(k)][c']
#define OFF_WNQ 4096
#define OFF_WNQL 8192
#define OFF_WNK 12288
#define OFF_WNKL 16384
#define OFF_WNV 20480
#define OFF_WNVL 24576
#define OFF_W4B 28672  // PERMUTED: W4B[c'][k] = W4[64+cb(k)][c']
#define OFF_W4T 32768
#define OFF_WSRC 36864
#define OFF_WSRCL 77824
#define OFF_WNQP 118784   // PERMUTED hi: Wnq[cb(k)][c']
#define OFF_WNQPL 122880  // PERMUTED lo
#define OFF_WNKP 126976
#define OFF_WNKPL 131072

typedef __attribute__((ext_vector_type(8))) short bf16x8;
typedef __attribute__((ext_vector_type(4))) float f32x4;
typedef __attribute__((ext_vector_type(4))) unsigned int u32x4;

__device__ __forceinline__ int rfl(int v) { return __builtin_amdgcn_readfirstlane(v); }

// Contraction-index permutation (r13-verified): position k (=32ks+8g+i) holds
// true channel cb(k) = 32ks + 16*(i>=4) + 4g + (i&3).
__device__ __forceinline__ int cbperm(int k) {
  return 32 * (k >> 5) + 16 * ((k >> 2) & 1) + 4 * ((k >> 3) & 3) + (k & 3);
}

__device__ __forceinline__ unsigned int rne16(float w) {
  unsigned int b = __float_as_uint(w);
  return (b + 0x7FFFu + ((b >> 16) & 1u)) >> 16;
}

__device__ __forceinline__ bf16x8 pack8(f32x4 a, f32x4 b) {
  u32x4 u;
  u[0] = (__float_as_uint(a[1]) & 0xFFFF0000u) | (__float_as_uint(a[0]) >> 16);
  u[1] = (__float_as_uint(a[3]) & 0xFFFF0000u) | (__float_as_uint(a[2]) >> 16);
  u[2] = (__float_as_uint(b[1]) & 0xFFFF0000u) | (__float_as_uint(b[0]) >> 16);
  u[3] = (__float_as_uint(b[3]) & 0xFFFF0000u) | (__float_as_uint(b[2]) >> 16);
  return __builtin_bit_cast(bf16x8, u);
}

__device__ __forceinline__ void split8(f32x4 a, f32x4 b, bf16x8& hi, bf16x8& lo) {
  unsigned int h[4], l[4];
#pragma unroll
  for (int j = 0; j < 2; ++j) {
    unsigned int b0 = __float_as_uint(a[2 * j]);
    unsigned int b1 = __float_as_uint(a[2 * j + 1]);
    h[j] = (b1 & 0xFFFF0000u) | (b0 >> 16);
    float r0 = a[2 * j] - __uint_as_float(b0 & 0xFFFF0000u);
    float r1 = a[2 * j + 1] - __uint_as_float(b1 & 0xFFFF0000u);
    l[j] = (__float_as_uint(r1) & 0xFFFF0000u) | (__float_as_uint(r0) >> 16);
  }
#pragma unroll
  for (int j = 0; j < 2; ++j) {
    unsigned int b0 = __float_as_uint(b[2 * j]);
    unsigned int b1 = __float_as_uint(b[2 * j + 1]);
    h[2 + j] = (b1 & 0xFFFF0000u) | (b0 >> 16);
    float r0 = b[2 * j] - __uint_as_float(b0 & 0xFFFF0000u);
    float r1 = b[2 * j + 1] - __uint_as_float(b1 & 0xFFFF0000u);
    l[2 + j] = (__float_as_uint(r1) & 0xFFFF0000u) | (__float_as_uint(r0) >> 16);
  }
  u32x4 uh = {h[0], h[1], h[2], h[3]};
  u32x4 ul = {l[0], l[1], l[2], l[3]};
  hi = __builtin_bit_cast(bf16x8, uh);
  lo = __builtin_bit_cast(bf16x8, ul);
}

// unpack 4 bf16 (uint2, low-first) -> f32x4
__device__ __forceinline__ f32x4 unpack4(uint2 u) {
  f32x4 o;
  o[0] = __uint_as_float(u.x << 16);
  o[1] = __uint_as_float(u.x & 0xFFFF0000u);
  o[2] = __uint_as_float(u.y << 16);
  o[3] = __uint_as_float(u.y & 0xFFFF0000u);
  return o;
}

__device__ __forceinline__ f32x4 relu4(f32x4 a, f32x4 b) {
  f32x4 o;
#pragma unroll
  for (int j = 0; j < 4; ++j) o[j] = fmaxf(a[j] + b[j], 0.f);
  return o;
}

// ---------------------------------------------------------------------------
__global__ void k_init(float* __restrict__ ws) {
  int t = blockIdx.x * 256 + threadIdx.x;
  int stride = gridDim.x * 256;
  for (int i = t; i < 130 * NN; i += stride)
    ws[i] = (i >= NN && i < 2 * NN) ? 1.0f : 0.0f;
}

// ---------------------------------------------------------------------------
__global__ void k_scatter(const int* __restrict__ ei, const float* __restrict__ ea,
                          float* __restrict__ deg, float* __restrict__ dout,
                          float* __restrict__ sum_in, float* __restrict__ sum_src) {
  int t = blockIdx.x * 256 + threadIdx.x;
  if (t >= EE * 64) return;
  int e = t >> 6, f = t & 63;
  int s = ei[e];
  int d = ei[EE + e];
  float v = ea[t];
  atomicAdd(&sum_in[d * 64 + f], v);
  atomicAdd(&sum_src[s * 64 + f], v);
  if (f == 0) {
    atomicAdd(&deg[d], 1.0f);
    atomicAdd(&dout[s], 1.0f);
  }
}

// ---------------------------------------------------------------------------
// y: 0=Wnq 1=Wnk 2=Wnv 3=W4bot(P) 4=W4top 5..14=Wsrc h=y-5, 15=W5(P)+Cg/Cb,
// 16=Wnq(P hi/lo), 17=Wnk(P hi/lo).
__global__ void k_prepall(const float* __restrict__ Wnq, const float* __restrict__ Wnk,
                          const float* __restrict__ Wnv, const float* __restrict__ W4,
                          const float* __restrict__ Wsrc, const float* __restrict__ W5,
                          const float* __restrict__ g1, const float* __restrict__ b1,
                          float* __restrict__ Cg, float* __restrict__ Cb,
                          unsigned short* __restrict__ wbuf) {
  const int c = blockIdx.x, f = threadIdx.x, y = blockIdx.y;
  if (y == 15) {
    const int cb = cbperm(f);
    float w = W5[cb * 64 + c];
    wbuf[OFF_W5T + c * 64 + f] = (unsigned short)rne16(w);
    float cg = g1[cb] * w;
    float cbb = b1[cb] * w;
#pragma unroll
    for (int off = 1; off < 64; off <<= 1) {
      cg += __shfl_xor(cg, off, 64);
      cbb += __shfl_xor(cbb, off, 64);
    }
    if (f == 0) {
      Cg[c] = cg;
      Cb[c] = cbb;
    }
    return;
  }
  float w;
  int hioff, looff = -1;
  const int cf = c * 64 + f;
  if (y == 0) { w = Wnq[f * 64 + c]; hioff = OFF_WNQ + cf; looff = OFF_WNQL + cf; }
  else if (y == 1) { w = Wnk[f * 64 + c]; hioff = OFF_WNK + cf; looff = OFF_WNKL + cf; }
  else if (y == 2) { w = Wnv[f * 64 + c]; hioff = OFF_WNV + cf; looff = OFF_WNVL + cf; }
  else if (y == 3) { w = W4[(64 + cbperm(f)) * 64 + c]; hioff = OFF_W4B + cf; }
  else if (y == 4) { w = W4[f * 64 + c]; hioff = OFF_W4T + cf; }
  else if (y == 16) { w = Wnq[cbperm(f) * 64 + c]; hioff = OFF_WNQP + cf; looff = OFF_WNQPL + cf; }
  else if (y == 17) { w = Wnk[cbperm(f) * 64 + c]; hioff = OFF_WNKP + cf; looff = OFF_WNKPL + cf; }
  else {
    int h = y - 5;
    w = Wsrc[f * 640 + h * 64 + c];
    hioff = OFF_WSRC + (h * 64 + c) * 64 + f;
    looff = OFF_WSRCL + (h * 64 + c) * 64 + f;
  }
  unsigned int hi = rne16(w);
  wbuf[hioff] = (unsigned short)hi;
  if (looff >= 0) {
    float rest = w - __uint_as_float(hi << 16);
    wbuf[looff] = (unsigned short)rne16(rest);
  }
}

// ---------------------------------------------------------------------------
// Fused xsrc + qk (r15-verified): per wave = 16 nodes, fixed head h.
__global__ __launch_bounds__(256) void k_xsrcq(const float* __restrict__ x,
                                               const unsigned short* __restrict__ wbuf,
                                               const float* __restrict__ eaQ,
                                               const float* __restrict__ eaK,
                                               const float* __restrict__ dout,
                                               float* __restrict__ xsrc,
                                               float* __restrict__ qk) {
  const int lane = threadIdx.x & 63;
  const int wv = rfl((int)threadIdx.x >> 6);
  const int g = lane >> 4, r = lane & 15;
  const int h = blockIdx.y;
  const int n0 = (blockIdx.x * 4 + wv) * 16;  // grid.x exact: NN/64
  const int n = n0 + r;
  bf16x8 whi[4][2], wlo[4][2];
#pragma unroll
  for (int mt = 0; mt < 4; ++mt)
#pragma unroll
    for (int ks = 0; ks < 2; ++ks) {
      const int off = (h * 64 + 16 * mt + r) * 64 + 32 * ks + 8 * g;
      whi[mt][ks] = *reinterpret_cast<const bf16x8*>(wbuf + OFF_WSRC + off);
      wlo[mt][ks] = *reinterpret_cast<const bf16x8*>(wbuf + OFF_WSRCL + off);
    }
  const float* xr = x + (size_t)n * 64 + 8 * g;
  bf16x8 xh0, xl0, xh1, xl1;
  split8(*reinterpret_cast<const f32x4*>(xr), *reinterpret_cast<const f32x4*>(xr + 4), xh0, xl0);
  split8(*reinterpret_cast<const f32x4*>(xr + 32), *reinterpret_cast<const f32x4*>(xr + 36), xh1, xl1);
  const size_t base = ((size_t)n * 10 + h) * 64;
  f32x4 d[4];
#pragma unroll
  for (int mt = 0; mt < 4; ++mt) {
    f32x4 a = {0, 0, 0, 0};
    a = __builtin_amdgcn_mfma_f32_16x16x32_bf16(whi[mt][0], xh0, a, 0, 0, 0);
    a = __builtin_amdgcn_mfma_f32_16x16x32_bf16(whi[mt][1], xh1, a, 0, 0, 0);
    a = __builtin_amdgcn_mfma_f32_16x16x32_bf16(whi[mt][0], xl0, a, 0, 0, 0);
    a = __builtin_amdgcn_mfma_f32_16x16x32_bf16(whi[mt][1], xl1, a, 0, 0, 0);
    a = __builtin_amdgcn_mfma_f32_16x16x32_bf16(wlo[mt][0], xh0, a, 0, 0, 0);
    a = __builtin_amdgcn_mfma_f32_16x16x32_bf16(wlo[mt][1], xh1, a, 0, 0, 0);
    d[mt] = a;
    *reinterpret_cast<f32x4*>(xsrc + base + 16 * mt + 4 * g) = a;
  }
  bf16x8 dh0, dl0, dh1, dl1;
  split8(d[0], d[1], dh0, dl0);
  split8(d[2], d[3], dh1, dl1);
  const float dn = dout[n];
  f32x4 qf[4];
#pragma unroll
  for (int mt = 0; mt < 4; ++mt) {
    const int off = (16 * mt + r) * 64 + 8 * g;
    bf16x8 ah0 = *reinterpret_cast<const bf16x8*>(wbuf + OFF_WNQP + off);
    bf16x8 ah1 = *reinterpret_cast<const bf16x8*>(wbuf + OFF_WNQP + off + 32);
    bf16x8 al0 = *reinterpret_cast<const bf16x8*>(wbuf + OFF_WNQPL + off);
    bf16x8 al1 = *reinterpret_cast<const bf16x8*>(wbuf + OFF_WNQPL + off + 32);
    f32x4 a = {0, 0, 0, 0};
    a = __builtin_amdgcn_mfma_f32_16x16x32_bf16(ah0, dh0, a, 0, 0, 0);
    a = __builtin_amdgcn_mfma_f32_16x16x32_bf16(ah1, dh1, a, 0, 0, 0);
    a = __builtin_amdgcn_mfma_f32_16x16x32_bf16(ah0, dl0, a, 0, 0, 0);
    a = __builtin_amdgcn_mfma_f32_16x16x32_bf16(ah1, dl1, a, 0, 0, 0);
    a = __builtin_amdgcn_mfma_f32_16x16x32_bf16(al0, dh0, a, 0, 0, 0);
    a = __builtin_amdgcn_mfma_f32_16x16x32_bf16(al1, dh1, a, 0, 0, 0);
    qf[mt] = a;
  }
  float p = 0.f;
#pragma unroll
  for (int mt = 0; mt < 4; ++mt) {
    const int off = (16 * mt + r) * 64 + 8 * g;
    bf16x8 ah0 = *reinterpret_cast<const bf16x8*>(wbuf + OFF_WNKP + off);
    bf16x8 ah1 = *reinterpret_cast<const bf16x8*>(wbuf + OFF_WNKP + off + 32);
    bf16x8 al0 = *reinterpret_cast<const bf16x8*>(wbuf + OFF_WNKPL + off);
    bf16x8 al1 = *reinterpret_cast<const bf16x8*>(wbuf + OFF_WNKPL + off + 32);
    f32x4 a = {0, 0, 0, 0};
    a = __builtin_amdgcn_mfma_f32_16x16x32_bf16(ah0, dh0, a, 0, 0, 0);
    a = __builtin_amdgcn_mfma_f32_16x16x32_bf16(ah1, dh1, a, 0, 0, 0);
    a = __builtin_amdgcn_mfma_f32_16x16x32_bf16(ah0, dl0, a, 0, 0, 0);
    a = __builtin_amdgcn_mfma_f32_16x16x32_bf16(ah1, dl1, a, 0, 0, 0);
    a = __builtin_amdgcn_mfma_f32_16x16x32_bf16(al0, dh0, a, 0, 0, 0);
    a = __builtin_amdgcn_mfma_f32_16x16x32_bf16(al1, dh1, a, 0, 0, 0);
    f32x4 eq = *reinterpret_cast<const f32x4*>(eaQ + (size_t)n * 64 + 16 * mt + 4 * g);
    f32x4 ek = *reinterpret_cast<const f32x4*>(eaK + (size_t)n * 64 + 16 * mt + 4 * g);
#pragma unroll
    for (int q = 0; q < 4; ++q) p = fmaf(qf[mt][q] + eq[q], fmaf(dn, a[q], ek[q]), p);
  }
  p += __shfl_xor(p, 16, 64);
  p += __shfl_xor(p, 32, 64);
  if (lane < 16) qk[(size_t)(n0 + lane) * HH + h] = p * 0.125f;
}

// ---------------------------------------------------------------------------
__global__ __launch_bounds__(256) void k_eaqkv(const float* __restrict__ deg,
                                               const float* __restrict__ sum_in,
                                               const float* __restrict__ sum_src,
                                               const float* __restrict__ Wek,
                                               const float* __restrict__ Weq,
                                               const float* __restrict__ Wev,
                                               float* __restrict__ eaQ,
                                               float* __restrict__ eaK,
                                               float* __restrict__ eaV) {
  const int lane = threadIdx.x & 63;
  const int wv = rfl(threadIdx.x >> 6);
  float wq[64], wk[64], wvv[64];
#pragma unroll
  for (int f = 0; f < 64; ++f) {
    wq[f] = Wek[f * 64 + lane];
    wk[f] = Weq[f * 64 + lane];
    wvv[f] = Wev[f * 64 + lane];
  }
  const int nw = gridDim.x * 4;
  for (int n = blockIdx.x * 4 + wv; n < NN; n += nw) {
    const float* si = sum_in + (size_t)n * 64;
    const float* ss = sum_src + (size_t)n * 64;
    const float invd = 1.0f / fmaxf(deg[n], 1.0f);
    float q0 = 0, q1 = 0, k0 = 0, k1 = 0, v0 = 0, v1 = 0;
#pragma unroll
    for (int f = 0; f < 64; f += 2) {
      float e0 = fmaf(si[f], invd, ss[f]);
      float e1 = fmaf(si[f + 1], invd, ss[f + 1]);
      q0 = fmaf(e0, wq[f], q0);
      q1 = fmaf(e1, wq[f + 1], q1);
      k0 = fmaf(e0, wk[f], k0);
      k1 = fmaf(e1, wk[f + 1], k1);
      v0 = fmaf(e0, wvv[f], v0);
      v1 = fmaf(e1, wvv[f + 1], v1);
    }
    eaQ[(size_t)n * 64 + lane] = q0 + q1;
    eaK[(size_t)n * 64 + lane] = k0 + k1;
    eaV[(size_t)n * 64 + lane] = v0 + v1;
  }
}

// ---------------------------------------------------------------------------
__global__ void k_softmax(const float* __restrict__ qk, float* __restrict__ sm) {
  int n = blockIdx.x * 256 + threadIdx.x;
  if (n >= NN) return;
  float v[HH];
  float mx = -1e30f;
#pragma unroll
  for (int h = 0; h < HH; ++h) {
    v[h] = qk[n * HH + h];
    mx = fmaxf(mx, v[h]);
  }
  float s = 0;
#pragma unroll
  for (int h = 0; h < HH; ++h) {
    v[h] = expf(v[h] - mx);
    s += v[h];
  }
  float inv = 1.0f / s;
#pragma unroll
  for (int h = 0; h < HH; ++h) sm[n * HH + h] = v[h] * inv;
}

// ---------------------------------------------------------------------------
// V = dout*(xsrc@Wnv)+eaV (3-term); nu = xsrc*sm*V (f32); node_out = nu+bias;
// NB (bf16, rne) = nu @ W4bot -- direct pack (cb-permuted W4B).
__global__ __launch_bounds__(256) void k_updm(const float* __restrict__ xsrc,
                                              const unsigned short* __restrict__ wbuf,
                                              const float* __restrict__ eaV,
                                              const float* __restrict__ dout,
                                              const float* __restrict__ sm,
                                              const float* __restrict__ bias,
                                              float* __restrict__ node_out,
                                              unsigned short* __restrict__ NBb) {
  const int lane = threadIdx.x & 63;
  const int wv = rfl((int)threadIdx.x >> 6);
  const int g = lane >> 4, r = lane & 15;
  const int grow = (blockIdx.x * 4 + wv) * 16 + r;  // grid exact: NN*HH/64
  const int n = grow / 10;
  const int h = grow - 10 * n;
  const float* xp = xsrc + (size_t)grow * 64;
  bf16x8 xh0, xl0, xh1, xl1;
  split8(*reinterpret_cast<const f32x4*>(xp + 8 * g), *reinterpret_cast<const f32x4*>(xp + 8 * g + 4),
         xh0, xl0);
  split8(*reinterpret_cast<const f32x4*>(xp + 8 * g + 32),
         *reinterpret_cast<const f32x4*>(xp + 8 * g + 36), xh1, xl1);
  const float dn = dout[n];
  const float wgt = sm[grow];
  f32x4 nu[4];
#pragma unroll
  for (int mt = 0; mt < 4; ++mt) {
    const int off = (16 * mt + r) * 64 + 8 * g;
    bf16x8 ah0 = *reinterpret_cast<const bf16x8*>(wbuf + OFF_WNV + off);
    bf16x8 ah1 = *reinterpret_cast<const bf16x8*>(wbuf + OFF_WNV + off + 32);
    bf16x8 al0 = *reinterpret_cast<const bf16x8*>(wbuf + OFF_WNVL + off);
    bf16x8 al1 = *reinterpret_cast<const bf16x8*>(wbuf + OFF_WNVL + off + 32);
    f32x4 vf = {0, 0, 0, 0};
    vf = __builtin_amdgcn_mfma_f32_16x16x32_bf16(ah0, xh0, vf, 0, 0, 0);
    vf = __builtin_amdgcn_mfma_f32_16x16x32_bf16(ah1, xh1, vf, 0, 0, 0);
    vf = __builtin_amdgcn_mfma_f32_16x16x32_bf16(ah0, xl0, vf, 0, 0, 0);
    vf = __builtin_amdgcn_mfma_f32_16x16x32_bf16(ah1, xl1, vf, 0, 0, 0);
    vf = __builtin_amdgcn_mfma_f32_16x16x32_bf16(al0, xh0, vf, 0, 0, 0);
    vf = __builtin_amdgcn_mfma_f32_16x16x32_bf16(al1, xh1, vf, 0, 0, 0);
    f32x4 ev = *reinterpret_cast<const f32x4*>(eaV + (size_t)n * 64 + 16 * mt + 4 * g);
    f32x4 xs = *reinterpret_cast<const f32x4*>(xp + 16 * mt + 4 * g);
    f32x4 nn;
#pragma unroll
    for (int q = 0; q < 4; ++q) nn[q] = xs[q] * wgt * fmaf(dn, vf[q], ev[q]);
    nu[mt] = nn;
    f32x4 bs = *reinterpret_cast<const f32x4*>(bias + h * 64 + 16 * mt + 4 * g);
    *reinterpret_cast<f32x4*>(node_out + (size_t)grow * 64 + 16 * mt + 4 * g) = nn + bs;
  }
  // NB feeds the W4B MFMA (direct pack via cb) AND bf16 global store
  bf16x8 nb0 = pack8(nu[0], nu[1]);
  bf16x8 nb1 = pack8(nu[2], nu[3]);
#pragma unroll
  for (int mt = 0; mt < 4; ++mt) {
    const int off = (16 * mt + r) * 64 + 8 * g;
    bf16x8 ba0 = *reinterpret_cast<const bf16x8*>(wbuf + OFF_W4B + off);
    bf16x8 ba1 = *reinterpret_cast<const bf16x8*>(wbuf + OFF_W4B + off + 32);
    f32x4 nf = {0, 0, 0, 0};
    nf = __builtin_amdgcn_mfma_f32_16x16x32_bf16(ba0, nb0, nf, 0, 0, 0);
    nf = __builtin_amdgcn_mfma_f32_16x16x32_bf16(ba1, nb1, nf, 0, 0, 0);
    uint2 o;
    o.x = (rne16(nf[1]) << 16) | rne16(nf[0]);
    o.y = (rne16(nf[3]) << 16) | rne16(nf[2]);
    *reinterpret_cast<uint2*>(NBb + (size_t)grow * 64 + 16 * mt + 4 * g) = o;
  }
}

// ---------------------------------------------------------------------------
// Edge MLP v13: r15 structure, NB gathered as bf16 (half bytes, half cache
// footprint -- the measured 3.5x HBM over-fetch on the src gather).
__global__ __launch_bounds__(256, 2) void k_edge10(
    const int* __restrict__ ei, const float* __restrict__ ea_g,
    const unsigned short* __restrict__ NBb, const unsigned short* __restrict__ wbuf,
    const float* __restrict__ Cgp, const float* __restrict__ Cbp,
    const float* __restrict__ g1v, const float* __restrict__ g2v,
    const float* __restrict__ bias2, float* __restrict__ edge_out) {
  const int lane = threadIdx.x & 63;
  const int wv = rfl((int)threadIdx.x >> 6);
  const int g = lane >> 4;
  const int r = lane & 15;
  const int e = (blockIdx.x * 4 + wv) * 16 + r;
  const int src = ei[e];

  bf16x8 whi[4][2];  // cb-permuted W5T
#pragma unroll
  for (int mt = 0; mt < 4; ++mt)
#pragma unroll
    for (int ks = 0; ks < 2; ++ks)
      whi[mt][ks] = *reinterpret_cast<const bf16x8*>(wbuf + OFF_W5T + (16 * mt + r) * 64 +
                                                     32 * ks + 8 * g);

  const float* EAr = ea_g + (size_t)e * 64;
  const float* ear = EAr + 8 * g;

  // hoisted loop invariants (C-layout)
  f32x4 eav[4], cbv[4], cgv[4], g1r[4], g2r[4], b2r[4];
#pragma unroll
  for (int mt = 0; mt < 4; ++mt) {
    eav[mt] = *reinterpret_cast<const f32x4*>(EAr + 16 * mt + 4 * g);
    cbv[mt] = *reinterpret_cast<const f32x4*>(Cbp + 16 * mt + 4 * g);
    cgv[mt] = *reinterpret_cast<const f32x4*>(Cgp + 16 * mt + 4 * g);
    g1r[mt] = *reinterpret_cast<const f32x4*>(g1v + 16 * mt + 4 * g);
    g2r[mt] = *reinterpret_cast<const f32x4*>(g2v + 16 * mt + 4 * g);
    b2r[mt] = *reinterpret_cast<const f32x4*>(bias2 + 16 * mt + 4 * g);
  }

  // fused A = ea @ W4top, KEPT in C-layout (feeds B1 via cb positions)
  f32x4 ad[4];
  {
    bf16x8 eb0 = pack8(*reinterpret_cast<const f32x4*>(ear),
                       *reinterpret_cast<const f32x4*>(ear + 4));
    bf16x8 eb1 = pack8(*reinterpret_cast<const f32x4*>(ear + 32),
                       *reinterpret_cast<const f32x4*>(ear + 36));
#pragma unroll
    for (int mt = 0; mt < 4; ++mt) {
      const int off = (16 * mt + r) * 64 + 8 * g;
      bf16x8 w0 = *reinterpret_cast<const bf16x8*>(wbuf + OFF_W4T + off);
      bf16x8 w1 = *reinterpret_cast<const bf16x8*>(wbuf + OFF_W4T + off + 32);
      f32x4 d = {0, 0, 0, 0};
      d = __builtin_amdgcn_mfma_f32_16x16x32_bf16(w0, eb0, d, 0, 0, 0);
      d = __builtin_amdgcn_mfma_f32_16x16x32_bf16(w1, eb1, d, 0, 0, 0);
      ad[mt] = d;
    }
  }

  const unsigned short* NBr = NBb + (size_t)src * 640;
  f32x4 outacc[4] = {{0, 0, 0, 0}, {0, 0, 0, 0}, {0, 0, 0, 0}, {0, 0, 0, 0}};

  // prologue: head 0's nb (bf16: 4 x uint2 per lane)
  uint2 c0 = *reinterpret_cast<const uint2*>(NBr + 4 * g);
  uint2 c1 = *reinterpret_cast<const uint2*>(NBr + 16 + 4 * g);
  uint2 c2 = *reinterpret_cast<const uint2*>(NBr + 32 + 4 * g);
  uint2 c3 = *reinterpret_cast<const uint2*>(NBr + 48 + 4 * g);

#pragma unroll 1
  for (int h = 0; h < HH; ++h) {
    uint2 p0, p1, p2, p3;
    if (h < HH - 1) {
      const unsigned short* nbn = NBr + (h + 1) * 64;
      p0 = *reinterpret_cast<const uint2*>(nbn + 4 * g);
      p1 = *reinterpret_cast<const uint2*>(nbn + 16 + 4 * g);
      p2 = *reinterpret_cast<const uint2*>(nbn + 32 + 4 * g);
      p3 = *reinterpret_cast<const uint2*>(nbn + 48 + 4 * g);
    } else {
      p0 = p1 = p2 = p3 = make_uint2(0, 0);
    }

    bf16x8 bhi0 = pack8(relu4(ad[0], unpack4(c0)), relu4(ad[1], unpack4(c1)));
    bf16x8 bhi1 = pack8(relu4(ad[2], unpack4(c2)), relu4(ad[3], unpack4(c3)));

    f32x4 acc1[4];
#pragma unroll
    for (int mt = 0; mt < 4; ++mt) {
      f32x4 a = eav[mt];
      a = __builtin_amdgcn_mfma_f32_16x16x32_bf16(whi[mt][0], bhi0, a, 0, 0, 0);
      a = __builtin_amdgcn_mfma_f32_16x16x32_bf16(whi[mt][1], bhi1, a, 0, 0, 0);
      acc1[mt] = a;
    }

    float s = 0.f, s2 = 0.f;
#pragma unroll
    for (int mt = 0; mt < 4; ++mt)
#pragma unroll
      for (int q = 0; q < 4; ++q) {
        float v = acc1[mt][q];
        s += v;
        s2 = fmaf(v, v, s2);
      }
    s += __shfl_xor(s, 16, 64);
    s2 += __shfl_xor(s2, 16, 64);
    s += __shfl_xor(s, 32, 64);
    s2 += __shfl_xor(s2, 32, 64);
    const float mu1 = s * 0.015625f;
    const float rs1 = rsqrtf(fmaxf(s2 * 0.015625f - mu1 * mu1, 1e-30f));

#pragma unroll
    for (int mt = 0; mt < 4; ++mt) acc1[mt] = acc1[mt] * g1r[mt] * rs1;
    bf16x8 b20 = pack8(acc1[0], acc1[1]);
    bf16x8 b21 = pack8(acc1[2], acc1[3]);

    const float m1r1 = mu1 * rs1;
    f32x4 acc2[4];
#pragma unroll
    for (int mt = 0; mt < 4; ++mt) {
      f32x4 a = eav[mt] + cbv[mt] - m1r1 * cgv[mt];
      a = __builtin_amdgcn_mfma_f32_16x16x32_bf16(whi[mt][0], b20, a, 0, 0, 0);
      a = __builtin_amdgcn_mfma_f32_16x16x32_bf16(whi[mt][1], b21, a, 0, 0, 0);
      acc2[mt] = a;
    }

    float t = 0.f, t2 = 0.f;
#pragma unroll
    for (int mt = 0; mt < 4; ++mt)
#pragma unroll
      for (int q = 0; q < 4; ++q) {
        float v = acc2[mt][q];
        t += v;
        t2 = fmaf(v, v, t2);
      }
    t += __shfl_xor(t, 16, 64);
    t2 += __shfl_xor(t2, 16, 64);
    t += __shfl_xor(t, 32, 64);
    t2 += __shfl_xor(t2, 32, 64);
    const float mu2 = t * 0.015625f;
    const float rs2 = rsqrtf(fmaxf(t2 * 0.015625f - mu2 * mu2, 1e-30f));
#pragma unroll
    for (int mt = 0; mt < 4; ++mt)
      outacc[mt] += (acc2[mt] - mu2) * rs2 * g2r[mt] + b2r[mt];

    c0 = p0; c1 = p1; c2 = p2; c3 = p3;
  }

#pragma unroll
  for (int mt = 0; mt < 4; ++mt) {
    f32x4 o = outacc[mt] * 0.1f;
    *reinterpret_cast<f32x4*>(edge_out + (size_t)e * 64 + 16 * mt + 4 * g) = o;
  }
}

// ---------------------------------------------------------------------------
extern "C" void kernel_launch(void* const* d_in, const int* in_sizes, int n_in,
                              void* d_out, int out_size, void* d_ws, size_t ws_size,
                              hipStream_t stream) {
  const float* x = (const float*)d_in[0];
  const int* ei = (const int*)d_in[1];
  const float* edge_attr = (const float*)d_in[2];
  const float* W_src = (const float*)d_in[3];
  const float* Wnq = (const float*)d_in[4];
  const float* Wnk = (const float*)d_in[5];
  const float* Wnv = (const float*)d_in[6];
  const float* Weq = (const float*)d_in[7];
  const float* Wev = (const float*)d_in[8];
  const float* Wek = (const float*)d_in[9];
  const float* W4 = (const float*)d_in[10];
  const float* W5 = (const float*)d_in[11];
  const float* g1 = (const float*)d_in[12];
  const float* b1 = (const float*)d_in[13];
  const float* g2 = (const float*)d_in[14];
  const float* b2 = (const float*)d_in[15];
  const float* bias = (const float*)d_in[16];
  (void)in_sizes; (void)n_in; (void)out_size; (void)ws_size;

  float* ws = (float*)d_ws;
  float* deg = ws;
  float* dout = ws + NN;
  float* sum_in = ws + 2 * NN;
  float* sum_src = ws + 66 * NN;
  unsigned short* wbuf = (unsigned short*)(ws + 130 * NN);
  float* eaQ = ws + 194 * NN;
  float* eaK = ws + 258 * NN;
  float* eaV = ws + 322 * NN;
  float* xsrc = ws + 386 * NN;
  unsigned short* NBb = (unsigned short*)(ws + 1026 * NN);  // 640*NN bf16 = 320*NN fl
  float* qk = ws + 1666 * NN;
  float* sm = ws + 1676 * NN;
  float* Cg = ws + 1686 * NN + 64 * EE;
  float* Cb = Cg + 64;

  float* node_out = (float*)d_out;
  float* edge_out = (float*)d_out + (size_t)NN * 640;

  k_init<<<1024, 256, 0, stream>>>(ws);
  k_prepall<<<dim3(64, 18), 64, 0, stream>>>(Wnq, Wnk, Wnv, W4, W_src, W5, g1, b1, Cg, Cb,
                                             wbuf);
  k_scatter<<<EE * 64 / 256, 256, 0, stream>>>(ei, edge_attr, deg, dout, sum_in, sum_src);
  k_eaqkv<<<250, 256, 0, stream>>>(deg, sum_in, sum_src, Wek, Weq, Wev, eaQ, eaK, eaV);
  k_xsrcq<<<dim3(NN / 64, 10), 256, 0, stream>>>(x, wbuf, eaQ, eaK, dout, xsrc, qk);
  k_softmax<<<(NN + 255) / 256, 256, 0, stream>>>(qk, sm);
  k_updm<<<NN * HH / 64, 256, 0, stream>>>(xsrc, wbuf, eaV, dout, sm, bias, node_out, NBb);
  k_edge10<<<EE / 64, 256, 0, stream>>>(ei, edge_attr, NBb, wbuf, Cg, Cb, g1, g2, b2,
                                        edge_out);
}